// Round 1
// baseline (410.182 us; speedup 1.0000x reference)
//
#include <hip/hip_runtime.h>
#include <hip/hip_bf16.h>
#include <stdint.h>
#include <math.h>

#define DIM   1024
#define TSEQ  2048
#define BATCH 2
#define NH    16
#define HD    64
#define FFN   4096
#define ROWS  (BATCH*TSEQ)   /* 4096 */
#define QKVN  (3*DIM)        /* 3072 */
#define GUN   (2*FFN)        /* 8192 */

typedef __attribute__((ext_vector_type(8))) short s16x8;
typedef __attribute__((ext_vector_type(4))) float f32x4;

__device__ __forceinline__ unsigned short f2bf(float f) {
  union { float f; unsigned u; } v; v.f = f;
  unsigned r = v.u + 0x7fffu + ((v.u >> 16) & 1u);
  return (unsigned short)(r >> 16);
}
__device__ __forceinline__ float bf2f(unsigned short h) {
  union { unsigned u; float f; } v; v.u = ((unsigned)h) << 16; return v.f;
}

__device__ __forceinline__ void gld16(const void* g, void* l) {
  __builtin_amdgcn_global_load_lds((const __attribute__((address_space(1))) void*)g,
                                   (__attribute__((address_space(3))) void*)l, 16, 0, 0);
}

// ---------------------------------------------------------------------------
// Weight transpose+cast: w [K][N] fp32 -> wt [N][K] bf16. grid (N/64, K/64)
// ---------------------------------------------------------------------------
__global__ void wtrans_k(const float* __restrict__ w, unsigned short* __restrict__ wt,
                         int K, int N)
{
  __shared__ unsigned short t[64][65];
  const int n0 = blockIdx.x * 64, k0 = blockIdx.y * 64;
  const int tid = threadIdx.x;
  #pragma unroll
  for (int i = 0; i < 16; ++i) {
    const int r = i*4 + (tid >> 6), c = tid & 63;   // r: k-local, c: n-local
    t[r][c] = f2bf(w[(size_t)(k0 + r) * N + n0 + c]);
  }
  __syncthreads();
  #pragma unroll
  for (int i = 0; i < 16; ++i) {
    const int r = i*4 + (tid >> 6), c = tid & 63;   // r: n-local, c: k-local
    wt[(size_t)(n0 + r) * K + k0 + c] = t[c][r];
  }
}

// ---------------------------------------------------------------------------
// V transpose: qkv [ROWS][3072] (v at col 2048) -> vt [32 bh][64 d][2048 t]
// grid (T/64, B*H)
// ---------------------------------------------------------------------------
__global__ void vtrans_k(const unsigned short* __restrict__ qkv, unsigned short* __restrict__ vt)
{
  __shared__ unsigned short t[64][65];
  const int tt0 = blockIdx.x * 64;
  const int bh = blockIdx.y, b = bh >> 4, h = bh & 15;
  const int tid = threadIdx.x;
  const unsigned short* src = qkv + (size_t)(b*TSEQ + tt0) * QKVN + 2*DIM + h*HD;
  #pragma unroll
  for (int i = 0; i < 16; ++i) {
    const int r = i*4 + (tid >> 6), c = tid & 63;   // r: t-local, c: d
    t[r][c] = src[(size_t)r * QKVN + c];
  }
  __syncthreads();
  unsigned short* dst = vt + (size_t)bh * HD * TSEQ + tt0;
  #pragma unroll
  for (int i = 0; i < 16; ++i) {
    const int d = i*4 + (tid >> 6), c = tid & 63;   // d: row, c: t-local
    dst[(size_t)d * TSEQ + c] = t[c][d];
  }
}

// ---------------------------------------------------------------------------
// RMSNorm: x [ROWS][DIM] fp32 -> out bf16. grid ROWS, block 256.
// ---------------------------------------------------------------------------
__global__ void rmsnorm_k(const float* __restrict__ x, const float* __restrict__ w,
                          unsigned short* __restrict__ o)
{
  const int row = blockIdx.x, tid = threadIdx.x;
  const float4 v = ((const float4*)(x + (size_t)row * DIM))[tid];
  float ss = v.x*v.x + v.y*v.y + v.z*v.z + v.w*v.w;
  #pragma unroll
  for (int off = 32; off >= 1; off >>= 1) ss += __shfl_xor(ss, off);
  __shared__ float sred[4];
  if ((tid & 63) == 0) sred[tid >> 6] = ss;
  __syncthreads();
  const float tot = sred[0] + sred[1] + sred[2] + sred[3];
  const float r = rsqrtf(tot * (1.0f/DIM) + 1e-6f);
  const float4 wv = ((const float4*)w)[tid];
  ushort4 ov;
  ov.x = f2bf(v.x*r*wv.x); ov.y = f2bf(v.y*r*wv.y);
  ov.z = f2bf(v.z*r*wv.z); ov.w = f2bf(v.w*r*wv.w);
  ((ushort4*)(o + (size_t)row * DIM))[tid] = ov;
}

// ---------------------------------------------------------------------------
// GEMM: C[M][N] = A[M][K]_bf16 @ BT[N][K]_bf16^T. 128x128 tile, BK=64, 4 waves.
// EPI 0: bf16 store. EPI 1: fp32 store = res + acc.
// grid (N/128, M/128), block 256.
// ---------------------------------------------------------------------------
template<int EPI>
__global__ void gemm128(const unsigned short* __restrict__ A, int lda,
                        const unsigned short* __restrict__ BT, int ldb,
                        void* __restrict__ Cout, int ldc,
                        const float* __restrict__ res, int K)
{
  __shared__ __align__(16) unsigned short lA[128*64];
  __shared__ __align__(16) unsigned short lB[128*64];
  const int tid = threadIdx.x;
  const int lane = tid & 63;
  const int wid = tid >> 6;
  const int m0 = blockIdx.y * 128, n0 = blockIdx.x * 128;
  const int wr = (wid >> 1) * 64, wc = (wid & 1) * 64;
  const int lrow = lane & 15, lk8 = (lane >> 4) * 8;

  f32x4 acc[4][4] = {};

  for (int k0 = 0; k0 < K; k0 += 64) {
    #pragma unroll
    for (int c = 0; c < 4; ++c) {
      const int boff = c*4096 + tid*16;
      const int row = boff >> 7, colb = boff & 127;
      gld16((const char*)A + ((size_t)(m0+row)*lda + k0)*2 + colb, (char*)lA + boff);
    }
    #pragma unroll
    for (int c = 0; c < 4; ++c) {
      const int boff = c*4096 + tid*16;
      const int row = boff >> 7, colb = boff & 127;
      gld16((const char*)BT + ((size_t)(n0+row)*ldb + k0)*2 + colb, (char*)lB + boff);
    }
    __syncthreads();
    #pragma unroll
    for (int kk = 0; kk < 64; kk += 32) {
      s16x8 af[4], bf[4];
      #pragma unroll
      for (int i = 0; i < 4; ++i) af[i] = *(const s16x8*)&lA[(wr + i*16 + lrow)*64 + kk + lk8];
      #pragma unroll
      for (int j = 0; j < 4; ++j) bf[j] = *(const s16x8*)&lB[(wc + j*16 + lrow)*64 + kk + lk8];
      #pragma unroll
      for (int i = 0; i < 4; ++i)
        #pragma unroll
        for (int j = 0; j < 4; ++j)
          acc[i][j] = __builtin_amdgcn_mfma_f32_16x16x32_bf16(af[i], bf[j], acc[i][j], 0, 0, 0);
    }
    __syncthreads();
  }
  // C/D layout: lane holds D[4*(lane>>4)+e][lane&15] of each 16x16 frag
  const int er = (lane >> 4) * 4, ec = lane & 15;
  #pragma unroll
  for (int i = 0; i < 4; ++i)
    #pragma unroll
    for (int j = 0; j < 4; ++j) {
      const int gr = m0 + wr + i*16 + er;
      const int gc = n0 + wc + j*16 + ec;
      #pragma unroll
      for (int e = 0; e < 4; ++e) {
        const size_t idx = (size_t)(gr + e) * ldc + gc;
        if (EPI == 0) ((unsigned short*)Cout)[idx] = f2bf(acc[i][j][e]);
        else          ((float*)Cout)[idx] = res[idx] + acc[i][j][e];
      }
    }
}

// ---------------------------------------------------------------------------
// Flash attention (causal). grid (T/64, B*H), block 256 (4 waves x 16 q-rows).
// qkv [ROWS][3072] bf16 (q@0, k@1024), vt [bh][64][2048] bf16, out [ROWS][DIM] bf16.
// Swapped QK^T: S' = K@Q^T so softmax state is lane-local in q = lane&15.
// ---------------------------------------------------------------------------
__global__ void attn_fwd(const unsigned short* __restrict__ qkv,
                         const unsigned short* __restrict__ vt,
                         unsigned short* __restrict__ outp)
{
  __shared__ __align__(16) unsigned short lK[32*64];   // [key][d]
  __shared__ __align__(16) unsigned short lV[64*32];   // [d][key]  (V^T)
  const int qblk = blockIdx.x;
  const int bh = blockIdx.y, b = bh >> 4, h = bh & 15;
  const int tid = threadIdx.x, wid = tid >> 6, lane = tid & 63;
  const int lq = lane & 15, g = lane >> 4;

  const int qrow = qblk*64 + wid*16;                       // wave q base (seq index)
  const size_t qbase = ((size_t)(b*TSEQ + qrow + lq)) * QKVN + h*HD;
  const s16x8 qf0 = *(const s16x8*)&qkv[qbase + g*8];
  const s16x8 qf1 = *(const s16x8*)&qkv[qbase + 32 + g*8];

  float mrun = -INFINITY, lrun = 0.f;
  f32x4 of[4] = {};                                        // O^T frags: of[d0b][e] = O^T[d0b*16+4g+e][lq]

  const int myq = qrow + lq;
  const int nkt = (qblk*64 + 64) >> 5;

  for (int kt = 0; kt < nkt; ++kt) {
    {
      const int boff = tid * 16;
      const int krow = boff >> 7, kcolb = boff & 127;
      gld16((const char*)qkv + ((size_t)(b*TSEQ + kt*32 + krow)*QKVN + DIM + h*HD)*2 + kcolb,
            (char*)lK + boff);
      const int vrow = boff >> 6, vcolb = boff & 63;
      gld16((const char*)vt + ((size_t)(bh*HD + vrow)*TSEQ + kt*32)*2 + vcolb,
            (char*)lV + boff);
    }
    __syncthreads();
    if (kt*32 <= qrow + 15) {
      f32x4 s0 = {0.f,0.f,0.f,0.f}, s1 = {0.f,0.f,0.f,0.f};
      s16x8 kf;
      kf = *(const s16x8*)&lK[(lq)*64      + g*8]; s0 = __builtin_amdgcn_mfma_f32_16x16x32_bf16(kf, qf0, s0, 0,0,0);
      kf = *(const s16x8*)&lK[(lq)*64 + 32 + g*8]; s0 = __builtin_amdgcn_mfma_f32_16x16x32_bf16(kf, qf1, s0, 0,0,0);
      kf = *(const s16x8*)&lK[(16+lq)*64      + g*8]; s1 = __builtin_amdgcn_mfma_f32_16x16x32_bf16(kf, qf0, s1, 0,0,0);
      kf = *(const s16x8*)&lK[(16+lq)*64 + 32 + g*8]; s1 = __builtin_amdgcn_mfma_f32_16x16x32_bf16(kf, qf1, s1, 0,0,0);
      // mask + scale; S' slab0 key-local = 4g+e, slab1 += 16; col q = lq
      float p0[4], p1[4];
      float mt = -INFINITY;
      #pragma unroll
      for (int e = 0; e < 4; ++e) {
        const int key0 = kt*32 + 4*g + e;
        const float v0 = (key0      <= myq) ? s0[e]*0.125f : -INFINITY;
        const float v1 = (key0 + 16 <= myq) ? s1[e]*0.125f : -INFINITY;
        p0[e] = v0; p1[e] = v1;
        mt = fmaxf(mt, fmaxf(v0, v1));
      }
      mt = fmaxf(mt, __shfl_xor(mt, 16));
      mt = fmaxf(mt, __shfl_xor(mt, 32));
      const float mnew = fmaxf(mrun, mt);
      const float scale = __expf(mrun - mnew);
      float ssum = 0.f;
      #pragma unroll
      for (int e = 0; e < 4; ++e) {
        p0[e] = __expf(p0[e] - mnew);
        p1[e] = __expf(p1[e] - mnew);
        ssum += p0[e] + p1[e];
      }
      ssum += __shfl_xor(ssum, 16);
      ssum += __shfl_xor(ssum, 32);
      lrun = lrun * scale + ssum;
      mrun = mnew;
      #pragma unroll
      for (int d0b = 0; d0b < 4; ++d0b) of[d0b] = of[d0b] * scale;
      // repack P into contiguous-8 B-frag: bp[e] = P[key = 8g+e][lq]
      s16x8 bp;
      #pragma unroll
      for (int e = 0; e < 8; ++e) {
        const int gsrc = (2*g + (e >> 2)) & 3;
        const int srcl = lq | (gsrc << 4);
        const float a0 = __shfl(p0[e & 3], srcl);
        const float a1 = __shfl(p1[e & 3], srcl);
        bp[e] = (short)f2bf((g >= 2) ? a1 : a0);
      }
      // PV: O^T += V^T @ P'   (A-frag = V^T rows d, k=key contiguous-8)
      #pragma unroll
      for (int d0b = 0; d0b < 4; ++d0b) {
        const s16x8 vf = *(const s16x8*)&lV[(d0b*16 + lq)*32 + 8*g];
        of[d0b] = __builtin_amdgcn_mfma_f32_16x16x32_bf16(vf, bp, of[d0b], 0, 0, 0);
      }
    }
    __syncthreads();
  }
  const float inv = 1.f / lrun;
  const size_t obase = ((size_t)(b*TSEQ + myq)) * DIM + h*HD;
  #pragma unroll
  for (int d0b = 0; d0b < 4; ++d0b) {
    ushort4 o;
    o.x = f2bf(of[d0b][0] * inv);
    o.y = f2bf(of[d0b][1] * inv);
    o.z = f2bf(of[d0b][2] * inv);
    o.w = f2bf(of[d0b][3] * inv);
    *(ushort4*)&outp[obase + d0b*16 + 4*g] = o;
  }
}

// ---------------------------------------------------------------------------
// SwiGLU elementwise: gu [ROWS][8192] bf16 (g | u); h -> g columns in place.
// ---------------------------------------------------------------------------
__global__ void silu_mul_k(unsigned short* __restrict__ gu)
{
  const size_t gid = (size_t)blockIdx.x * 256 + threadIdx.x;   // ROWS*DIM groups of 4
  const size_t r = gid >> 10;
  const int c4 = (int)(gid & 1023) * 4;
  unsigned short* gp = gu + r * GUN + c4;
  const ushort4 gv = *(const ushort4*)gp;
  const ushort4 uv = *(const ushort4*)(gp + FFN);
  float gf, hf;
  ushort4 hv;
  gf = bf2f(gv.x); hf = gf / (1.f + __expf(-gf)) * bf2f(uv.x); hv.x = f2bf(hf);
  gf = bf2f(gv.y); hf = gf / (1.f + __expf(-gf)) * bf2f(uv.y); hv.y = f2bf(hf);
  gf = bf2f(gv.z); hf = gf / (1.f + __expf(-gf)) * bf2f(uv.z); hv.z = f2bf(hf);
  gf = bf2f(gv.w); hf = gf / (1.f + __expf(-gf)) * bf2f(uv.w); hv.w = f2bf(hf);
  *(ushort4*)gp = hv;
}

// ---------------------------------------------------------------------------
extern "C" void kernel_launch(void* const* d_in, const int* in_sizes, int n_in,
                              void* d_out, int out_size, void* d_ws, size_t ws_size,
                              hipStream_t stream)
{
  const float* x   = (const float*)d_in[0];
  const float* wq  = (const float*)d_in[1];
  const float* wk  = (const float*)d_in[2];
  const float* wv  = (const float*)d_in[3];
  const float* wo  = (const float*)d_in[4];
  const float* wg  = (const float*)d_in[5];
  const float* wu  = (const float*)d_in[6];
  const float* wd  = (const float*)d_in[7];
  const float* anw = (const float*)d_in[8];
  const float* fnw = (const float*)d_in[9];
  float* outp = (float*)d_out;

  const size_t MB = 1024*1024;
  char* ws = (char*)d_ws;
  unsigned short* wqkvT = (unsigned short*)(ws + 0);        // [3072][1024] 6MB
  unsigned short* woT   = (unsigned short*)(ws + 6*MB);     // [1024][1024] 2MB
  unsigned short* wguT  = (unsigned short*)(ws + 8*MB);     // [8192][1024] 16MB
  unsigned short* wdT   = (unsigned short*)(ws + 24*MB);    // [1024][4096] 8MB
  unsigned short* xn    = (unsigned short*)(ws + 32*MB);    // [4096][1024] 8MB
  float*          x1    = (float*)         (ws + 40*MB);    // [4096][1024] fp32 16MB
  unsigned short* qkv   = (unsigned short*)(ws + 56*MB);    // [4096][3072] 24MB
  unsigned short* vtb   = (unsigned short*)(ws + 80*MB);    // [32][64][2048] 8MB
  unsigned short* aout  = (unsigned short*)(ws + 88*MB);    // [4096][1024] 8MB
  unsigned short* gu    = (unsigned short*)(ws + 56*MB);    // [4096][8192] 64MB (aliases qkv/vt/aout)

  const dim3 blk(256);

  // weights -> K-major bf16
  wtrans_k<<<dim3(16,16), blk, 0, stream>>>(wq, wqkvT,               DIM, DIM);
  wtrans_k<<<dim3(16,16), blk, 0, stream>>>(wk, wqkvT + 1024*1024,   DIM, DIM);
  wtrans_k<<<dim3(16,16), blk, 0, stream>>>(wv, wqkvT + 2*1024*1024, DIM, DIM);
  wtrans_k<<<dim3(16,16), blk, 0, stream>>>(wo, woT,                 DIM, DIM);
  wtrans_k<<<dim3(64,16), blk, 0, stream>>>(wg, wguT,               DIM, FFN);
  wtrans_k<<<dim3(64,16), blk, 0, stream>>>(wu, wguT + 4096*1024,   DIM, FFN);
  wtrans_k<<<dim3(16,64), blk, 0, stream>>>(wd, wdT,                FFN, DIM);

  // attn path
  rmsnorm_k<<<ROWS, blk, 0, stream>>>(x, anw, xn);
  gemm128<0><<<dim3(QKVN/128, ROWS/128), blk, 0, stream>>>(xn, DIM, wqkvT, DIM, qkv, QKVN, nullptr, DIM);
  vtrans_k<<<dim3(TSEQ/64, BATCH*NH), blk, 0, stream>>>(qkv, vtb);
  attn_fwd<<<dim3(TSEQ/64, BATCH*NH), blk, 0, stream>>>(qkv, vtb, aout);
  gemm128<1><<<dim3(DIM/128, ROWS/128), blk, 0, stream>>>(aout, DIM, woT, DIM, x1, DIM, x, DIM);

  // ffn path
  rmsnorm_k<<<ROWS, blk, 0, stream>>>(x1, fnw, xn);
  gemm128<0><<<dim3(GUN/128, ROWS/128), blk, 0, stream>>>(xn, DIM, wguT, DIM, gu, GUN, nullptr, DIM);
  silu_mul_k<<<dim3(ROWS*DIM/256), blk, 0, stream>>>(gu);
  gemm128<1><<<dim3(DIM/128, ROWS/128), blk, 0, stream>>>(gu, GUN, wdT, FFN, (void*)outp, DIM, x1, FFN);
}

// Round 2
// 364.249 us; speedup vs baseline: 1.1261x; 1.1261x over previous
//
#include <hip/hip_runtime.h>
#include <hip/hip_bf16.h>
#include <stdint.h>
#include <math.h>

#define DIM   1024
#define TSEQ  2048
#define BATCH 2
#define NH    16
#define HD    64
#define FFN   4096
#define ROWS  (BATCH*TSEQ)   /* 4096 */
#define QKVN  (3*DIM)        /* 3072 */
#define GUN   (2*FFN)        /* 8192 */

typedef __attribute__((ext_vector_type(8))) short s16x8;
typedef __attribute__((ext_vector_type(4))) float f32x4;

__device__ __forceinline__ unsigned short f2bf(float f) {
  union { float f; unsigned u; } v; v.f = f;
  unsigned r = v.u + 0x7fffu + ((v.u >> 16) & 1u);
  return (unsigned short)(r >> 16);
}
__device__ __forceinline__ float bf2f(unsigned short h) {
  union { unsigned u; float f; } v; v.u = ((unsigned)h) << 16; return v.f;
}
// pack two f32 -> u32 of 2 bf16 (truncate): lo in bits 0-15, hi in 16-31
__device__ __forceinline__ unsigned pack_bf2(float lo, float hi) {
  union { float f; unsigned u; } a, c; a.f = lo; c.f = hi;
  return (c.u & 0xffff0000u) | (a.u >> 16);
}

__device__ __forceinline__ void gld16(const void* g, void* l) {
  __builtin_amdgcn_global_load_lds((const __attribute__((address_space(1))) void*)g,
                                   (__attribute__((address_space(3))) void*)l, 16, 0, 0);
}

// ---------------------------------------------------------------------------
// Weight transpose+cast: w [K][N] fp32 -> wt [N][K] bf16. grid (N/64, K/64)
// ---------------------------------------------------------------------------
__global__ void wtrans_k(const float* __restrict__ w, unsigned short* __restrict__ wt,
                         int K, int N)
{
  __shared__ unsigned short t[64][65];
  const int n0 = blockIdx.x * 64, k0 = blockIdx.y * 64;
  const int tid = threadIdx.x;
  #pragma unroll
  for (int i = 0; i < 16; ++i) {
    const int r = i*4 + (tid >> 6), c = tid & 63;
    t[r][c] = f2bf(w[(size_t)(k0 + r) * N + n0 + c]);
  }
  __syncthreads();
  #pragma unroll
  for (int i = 0; i < 16; ++i) {
    const int r = i*4 + (tid >> 6), c = tid & 63;
    wt[(size_t)(n0 + r) * K + k0 + c] = t[c][r];
  }
}

// ---------------------------------------------------------------------------
// V transpose: qkv [ROWS][3072] (v at col 2048) -> vt [32 bh][64 d][2048 t]
// ---------------------------------------------------------------------------
__global__ void vtrans_k(const unsigned short* __restrict__ qkv, unsigned short* __restrict__ vt)
{
  __shared__ unsigned short t[64][65];
  const int tt0 = blockIdx.x * 64;
  const int bh = blockIdx.y, b = bh >> 4, h = bh & 15;
  const int tid = threadIdx.x;
  const unsigned short* src = qkv + (size_t)(b*TSEQ + tt0) * QKVN + 2*DIM + h*HD;
  #pragma unroll
  for (int i = 0; i < 16; ++i) {
    const int r = i*4 + (tid >> 6), c = tid & 63;
    t[r][c] = src[(size_t)r * QKVN + c];
  }
  __syncthreads();
  unsigned short* dst = vt + (size_t)bh * HD * TSEQ + tt0;
  #pragma unroll
  for (int i = 0; i < 16; ++i) {
    const int d = i*4 + (tid >> 6), c = tid & 63;
    dst[(size_t)d * TSEQ + c] = t[c][d];
  }
}

// ---------------------------------------------------------------------------
// RMSNorm: x [ROWS][DIM] fp32 -> out bf16. grid ROWS, block 256.
// ---------------------------------------------------------------------------
__global__ void rmsnorm_k(const float* __restrict__ x, const float* __restrict__ w,
                          unsigned short* __restrict__ o)
{
  const int row = blockIdx.x, tid = threadIdx.x;
  const float4 v = ((const float4*)(x + (size_t)row * DIM))[tid];
  float ss = v.x*v.x + v.y*v.y + v.z*v.z + v.w*v.w;
  #pragma unroll
  for (int off = 32; off >= 1; off >>= 1) ss += __shfl_xor(ss, off);
  __shared__ float sred[4];
  if ((tid & 63) == 0) sred[tid >> 6] = ss;
  __syncthreads();
  const float tot = sred[0] + sred[1] + sred[2] + sred[3];
  const float r = rsqrtf(tot * (1.0f/DIM) + 1e-6f);
  const float4 wv = ((const float4*)w)[tid];
  ushort4 ov;
  ov.x = f2bf(v.x*r*wv.x); ov.y = f2bf(v.y*r*wv.y);
  ov.z = f2bf(v.z*r*wv.z); ov.w = f2bf(v.w*r*wv.w);
  ((ushort4*)(o + (size_t)row * DIM))[tid] = ov;
}

// ---------------------------------------------------------------------------
// GEMM: C[M][N] = A[M][K]_bf16 @ BT[N][K]_bf16^T. 128x128 tile, BK=64, 4 waves.
// ---------------------------------------------------------------------------
template<int EPI>
__global__ void gemm128(const unsigned short* __restrict__ A, int lda,
                        const unsigned short* __restrict__ BT, int ldb,
                        void* __restrict__ Cout, int ldc,
                        const float* __restrict__ res, int K)
{
  __shared__ __align__(16) unsigned short lA[128*64];
  __shared__ __align__(16) unsigned short lB[128*64];
  const int tid = threadIdx.x;
  const int lane = tid & 63;
  const int wid = tid >> 6;
  const int m0 = blockIdx.y * 128, n0 = blockIdx.x * 128;
  const int wr = (wid >> 1) * 64, wc = (wid & 1) * 64;
  const int lrow = lane & 15, lk8 = (lane >> 4) * 8;

  f32x4 acc[4][4] = {};

  for (int k0 = 0; k0 < K; k0 += 64) {
    #pragma unroll
    for (int c = 0; c < 4; ++c) {
      const int boff = c*4096 + tid*16;
      const int row = boff >> 7, colb = boff & 127;
      gld16((const char*)A + ((size_t)(m0+row)*lda + k0)*2 + colb, (char*)lA + boff);
    }
    #pragma unroll
    for (int c = 0; c < 4; ++c) {
      const int boff = c*4096 + tid*16;
      const int row = boff >> 7, colb = boff & 127;
      gld16((const char*)BT + ((size_t)(n0+row)*ldb + k0)*2 + colb, (char*)lB + boff);
    }
    __syncthreads();
    #pragma unroll
    for (int kk = 0; kk < 64; kk += 32) {
      s16x8 af[4], bf[4];
      #pragma unroll
      for (int i = 0; i < 4; ++i) af[i] = *(const s16x8*)&lA[(wr + i*16 + lrow)*64 + kk + lk8];
      #pragma unroll
      for (int j = 0; j < 4; ++j) bf[j] = *(const s16x8*)&lB[(wc + j*16 + lrow)*64 + kk + lk8];
      #pragma unroll
      for (int i = 0; i < 4; ++i)
        #pragma unroll
        for (int j = 0; j < 4; ++j)
          acc[i][j] = __builtin_amdgcn_mfma_f32_16x16x32_bf16(af[i], bf[j], acc[i][j], 0, 0, 0);
    }
    __syncthreads();
  }
  const int er = (lane >> 4) * 4, ec = lane & 15;
  #pragma unroll
  for (int i = 0; i < 4; ++i)
    #pragma unroll
    for (int j = 0; j < 4; ++j) {
      const int gr = m0 + wr + i*16 + er;
      const int gc = n0 + wc + j*16 + ec;
      #pragma unroll
      for (int e = 0; e < 4; ++e) {
        const size_t idx = (size_t)(gr + e) * ldc + gc;
        if (EPI == 0) ((unsigned short*)Cout)[idx] = f2bf(acc[i][j][e]);
        else          ((float*)Cout)[idx] = res[idx] + acc[i][j][e];
      }
    }
}

// ---------------------------------------------------------------------------
// Flash attention v2 (causal). grid (T/128, B*H), block 512 (8 waves x 16 q).
// KVBLK=64, double-buffered LDS, XOR-swizzled K/V tiles (both-sides).
// Swapped QK^T: S' = K@Q^T so softmax state is lane-local in q = lane&15.
// lK logical [64 key][64 d], lV logical [64 d][64 key]; phys byte =
// logical_byte ^ ((row&7)<<4).
// ---------------------------------------------------------------------------
__global__ __launch_bounds__(512) void attn_fwd(const unsigned short* __restrict__ qkv,
                                                const unsigned short* __restrict__ vt,
                                                unsigned short* __restrict__ outp)
{
  __shared__ __align__(16) unsigned short lK[2][64*64];
  __shared__ __align__(16) unsigned short lV[2][64*64];
  const int qblk = blockIdx.x;
  const int bh = blockIdx.y, b = bh >> 4, h = bh & 15;
  const int tid = threadIdx.x, wid = tid >> 6, lane = tid & 63;
  const int lq = lane & 15, g = lane >> 4;

  const int qrow = qblk*128 + wid*16;
  const int myq = qrow + lq;

  // Q fragments (from global; one-time)
  const size_t qbase = ((size_t)(b*TSEQ + myq)) * QKVN + h*HD;
  const s16x8 qf0 = *(const s16x8*)&qkv[qbase + g*8];
  const s16x8 qf1 = *(const s16x8*)&qkv[qbase + 32 + g*8];

  // staging addresses: phys dest boff is linear, source uses unswizzled loff
  const int boff = tid * 16;
  const int loff = boff ^ (((boff >> 7) & 7) << 4);
  const int srow = loff >> 7;        // 0..63 (same as boff>>7)
  const int scolb = loff & 127;      // byte col within row
  const char* ksrc0 = (const char*)qkv +
      (((size_t)(b*TSEQ + srow)) * QKVN + DIM + h*HD) * 2 + scolb;
  const char* vsrc0 = (const char*)vt +
      (((size_t)bh*HD + srow) * TSEQ) * 2 + scolb;

  float mrun = -INFINITY, lrun = 0.f;
  f32x4 of[4] = {};                  // of[d0b][e] = O^T[d0b*16+4g+e][lq]

  const int nkt = 2*qblk + 2;

  // prologue: stage tile 0 into buffer 0
  gld16(ksrc0, (char*)lK[0] + boff);
  gld16(vsrc0, (char*)lV[0] + boff);
  int cur = 0;

  for (int kt = 0; kt < nkt; ++kt) {
    __syncthreads();   // drains stage(kt); also fences compute(kt-1) reads
    if (kt + 1 < nkt) {
      gld16(ksrc0 + (size_t)(kt+1)*64*(QKVN*2), (char*)lK[cur^1] + boff);
      gld16(vsrc0 + (size_t)(kt+1)*128,         (char*)lV[cur^1] + boff);
    }
    if (kt*64 <= qrow + 15) {
      const unsigned short* Kb = lK[cur];
      const unsigned short* Vb = lV[cur];
      // QK^T: S'[key][q], 4 slabs of 16 keys
      f32x4 sacc[4] = {};
      #pragma unroll
      for (int s = 0; s < 4; ++s) {
        const int r = s*16 + lq;
        const int sw = (r & 7) << 4;
        const s16x8 kf0 = *(const s16x8*)((const char*)Kb + r*128 + ((g*16) ^ sw));
        const s16x8 kf1 = *(const s16x8*)((const char*)Kb + r*128 + ((64 + g*16) ^ sw));
        sacc[s] = __builtin_amdgcn_mfma_f32_16x16x32_bf16(kf0, qf0, sacc[s], 0,0,0);
        sacc[s] = __builtin_amdgcn_mfma_f32_16x16x32_bf16(kf1, qf1, sacc[s], 0,0,0);
      }
      // mask + scale; lane holds keys kt*64 + s*16 + 4g + e, column q = lq
      float p[4][4];
      float mt = -INFINITY;
      #pragma unroll
      for (int s = 0; s < 4; ++s)
        #pragma unroll
        for (int e = 0; e < 4; ++e) {
          const int key = kt*64 + s*16 + 4*g + e;
          const float v = (key <= myq) ? sacc[s][e]*0.125f : -INFINITY;
          p[s][e] = v;
          mt = fmaxf(mt, v);
        }
      mt = fmaxf(mt, __shfl_xor(mt, 16));
      mt = fmaxf(mt, __shfl_xor(mt, 32));
      const float mnew = fmaxf(mrun, mt);
      const float scale = __expf(mrun - mnew);
      float ssum = 0.f;
      #pragma unroll
      for (int s = 0; s < 4; ++s)
        #pragma unroll
        for (int e = 0; e < 4; ++e) {
          p[s][e] = __expf(p[s][e] - mnew);
          ssum += p[s][e];
        }
      ssum += __shfl_xor(ssum, 16);
      ssum += __shfl_xor(ssum, 32);
      lrun = lrun * scale + ssum;
      mrun = mnew;
      #pragma unroll
      for (int d0b = 0; d0b < 4; ++d0b) of[d0b] = of[d0b] * scale;
      // repack + PV per 32-key half. Slabs 2h (lo16) and 2h+1 (hi16) packed
      // into one u32 so one shuffle serves both; reader picks half by g.
      #pragma unroll
      for (int hh = 0; hh < 2; ++hh) {
        unsigned w[4];
        #pragma unroll
        for (int j = 0; j < 4; ++j) w[j] = pack_bf2(p[2*hh][j], p[2*hh+1][j]);
        s16x8 bp;
        #pragma unroll
        for (int e = 0; e < 8; ++e) {
          const int srcg = 2*(g & 1) + (e >> 2);
          const unsigned ww = (unsigned)__shfl((int)w[e & 3], lq | (srcg << 4));
          bp[e] = (short)((g >= 2) ? (ww >> 16) : (ww & 0xffffu));
        }
        #pragma unroll
        for (int d0b = 0; d0b < 4; ++d0b) {
          const int r = d0b*16 + lq;
          const int sw = (r & 7) << 4;
          const s16x8 vf = *(const s16x8*)((const char*)Vb + r*128 + ((hh*64 + g*16) ^ sw));
          of[d0b] = __builtin_amdgcn_mfma_f32_16x16x32_bf16(vf, bp, of[d0b], 0,0,0);
        }
      }
    }
    cur ^= 1;
  }
  const float inv = 1.f / lrun;
  const size_t obase = ((size_t)(b*TSEQ + myq)) * DIM + h*HD;
  #pragma unroll
  for (int d0b = 0; d0b < 4; ++d0b) {
    ushort4 o;
    o.x = f2bf(of[d0b][0] * inv);
    o.y = f2bf(of[d0b][1] * inv);
    o.z = f2bf(of[d0b][2] * inv);
    o.w = f2bf(of[d0b][3] * inv);
    *(ushort4*)&outp[obase + d0b*16 + 4*g] = o;
  }
}

// ---------------------------------------------------------------------------
// SwiGLU elementwise: gu [ROWS][8192] bf16 (g | u); h -> g columns in place.
// ---------------------------------------------------------------------------
__global__ void silu_mul_k(unsigned short* __restrict__ gu)
{
  const size_t gid = (size_t)blockIdx.x * 256 + threadIdx.x;
  const size_t r = gid >> 10;
  const int c4 = (int)(gid & 1023) * 4;
  unsigned short* gp = gu + r * GUN + c4;
  const ushort4 gv = *(const ushort4*)gp;
  const ushort4 uv = *(const ushort4*)(gp + FFN);
  float gf, hf;
  ushort4 hv;
  gf = bf2f(gv.x); hf = gf / (1.f + __expf(-gf)) * bf2f(uv.x); hv.x = f2bf(hf);
  gf = bf2f(gv.y); hf = gf / (1.f + __expf(-gf)) * bf2f(uv.y); hv.y = f2bf(hf);
  gf = bf2f(gv.z); hf = gf / (1.f + __expf(-gf)) * bf2f(uv.z); hv.z = f2bf(hf);
  gf = bf2f(gv.w); hf = gf / (1.f + __expf(-gf)) * bf2f(uv.w); hv.w = f2bf(hf);
  *(ushort4*)gp = hv;
}

// ---------------------------------------------------------------------------
extern "C" void kernel_launch(void* const* d_in, const int* in_sizes, int n_in,
                              void* d_out, int out_size, void* d_ws, size_t ws_size,
                              hipStream_t stream)
{
  const float* x   = (const float*)d_in[0];
  const float* wq  = (const float*)d_in[1];
  const float* wk  = (const float*)d_in[2];
  const float* wv  = (const float*)d_in[3];
  const float* wo  = (const float*)d_in[4];
  const float* wg  = (const float*)d_in[5];
  const float* wu  = (const float*)d_in[6];
  const float* wd  = (const float*)d_in[7];
  const float* anw = (const float*)d_in[8];
  const float* fnw = (const float*)d_in[9];
  float* outp = (float*)d_out;

  const size_t MB = 1024*1024;
  char* ws = (char*)d_ws;
  unsigned short* wqkvT = (unsigned short*)(ws + 0);        // [3072][1024] 6MB
  unsigned short* woT   = (unsigned short*)(ws + 6*MB);     // [1024][1024] 2MB
  unsigned short* wguT  = (unsigned short*)(ws + 8*MB);     // [8192][1024] 16MB
  unsigned short* wdT   = (unsigned short*)(ws + 24*MB);    // [1024][4096] 8MB
  unsigned short* xn    = (unsigned short*)(ws + 32*MB);    // [4096][1024] 8MB
  float*          x1    = (float*)         (ws + 40*MB);    // [4096][1024] fp32 16MB
  unsigned short* qkv   = (unsigned short*)(ws + 56*MB);    // [4096][3072] 24MB
  unsigned short* vtb   = (unsigned short*)(ws + 80*MB);    // [32][64][2048] 8MB
  unsigned short* aout  = (unsigned short*)(ws + 88*MB);    // [4096][1024] 8MB
  unsigned short* gu    = (unsigned short*)(ws + 56*MB);    // [4096][8192] 64MB (aliases qkv/vt/aout)

  const dim3 blk(256);

  wtrans_k<<<dim3(16,16), blk, 0, stream>>>(wq, wqkvT,               DIM, DIM);
  wtrans_k<<<dim3(16,16), blk, 0, stream>>>(wk, wqkvT + 1024*1024,   DIM, DIM);
  wtrans_k<<<dim3(16,16), blk, 0, stream>>>(wv, wqkvT + 2*1024*1024, DIM, DIM);
  wtrans_k<<<dim3(16,16), blk, 0, stream>>>(wo, woT,                 DIM, DIM);
  wtrans_k<<<dim3(64,16), blk, 0, stream>>>(wg, wguT,               DIM, FFN);
  wtrans_k<<<dim3(64,16), blk, 0, stream>>>(wu, wguT + 4096*1024,   DIM, FFN);
  wtrans_k<<<dim3(16,64), blk, 0, stream>>>(wd, wdT,                FFN, DIM);

  rmsnorm_k<<<ROWS, blk, 0, stream>>>(x, anw, xn);
  gemm128<0><<<dim3(QKVN/128, ROWS/128), blk, 0, stream>>>(xn, DIM, wqkvT, DIM, qkv, QKVN, nullptr, DIM);
  vtrans_k<<<dim3(TSEQ/64, BATCH*NH), blk, 0, stream>>>(qkv, vtb);
  attn_fwd<<<dim3(TSEQ/128, BATCH*NH), dim3(512), 0, stream>>>(qkv, vtb, aout);
  gemm128<1><<<dim3(DIM/128, ROWS/128), blk, 0, stream>>>(aout, DIM, woT, DIM, x1, DIM, x, DIM);

  rmsnorm_k<<<ROWS, blk, 0, stream>>>(x1, fnw, xn);
  gemm128<0><<<dim3(GUN/128, ROWS/128), blk, 0, stream>>>(xn, DIM, wguT, DIM, gu, GUN, nullptr, DIM);
  silu_mul_k<<<dim3(ROWS*DIM/256), blk, 0, stream>>>(gu);
  gemm128<1><<<dim3(DIM/128, ROWS/128), blk, 0, stream>>>(gu, GUN, wdT, FFN, (void*)outp, DIM, x1, FFN);
}

// Round 4
// 361.801 us; speedup vs baseline: 1.1337x; 1.0068x over previous
//
#include <hip/hip_runtime.h>
#include <hip/hip_bf16.h>
#include <stdint.h>
#include <math.h>

#define DIM   1024
#define TSEQ  2048
#define BATCH 2
#define NH    16
#define HD    64
#define FFN   4096
#define ROWS  (BATCH*TSEQ)   /* 4096 */
#define QKVN  (3*DIM)        /* 3072 */

typedef __attribute__((ext_vector_type(8))) short s16x8;
typedef __attribute__((ext_vector_type(4))) float f32x4;

__device__ __forceinline__ unsigned short f2bf(float f) {
  union { float f; unsigned u; } v; v.f = f;
  unsigned r = v.u + 0x7fffu + ((v.u >> 16) & 1u);
  return (unsigned short)(r >> 16);
}
__device__ __forceinline__ float bf2f(unsigned short h) {
  union { unsigned u; float f; } v; v.u = ((unsigned)h) << 16; return v.f;
}
__device__ __forceinline__ unsigned pack_bf2(float lo, float hi) {
  union { float f; unsigned u; } a, c; a.f = lo; c.f = hi;
  return (c.u & 0xffff0000u) | (a.u >> 16);
}

__device__ __forceinline__ void gld16(const void* g, void* l) {
  __builtin_amdgcn_global_load_lds((const __attribute__((address_space(1))) void*)g,
                                   (__attribute__((address_space(3))) void*)l, 16, 0, 0);
}

// ---------------------------------------------------------------------------
// Weight transpose+cast: w [K][N] fp32 -> wt [dest(n)][K] bf16. grid (N/64,K/64)
// mode 0: dest=n. mode 1 (gate): dest=(n>>4)*32+(n&15). mode 2 (up): +16.
// ---------------------------------------------------------------------------
__global__ void wtrans_k(const float* __restrict__ w, unsigned short* __restrict__ wt,
                         int K, int N, int mode)
{
  __shared__ unsigned short t[64][65];
  const int n0 = blockIdx.x * 64, k0 = blockIdx.y * 64;
  const int tid = threadIdx.x;
  #pragma unroll
  for (int i = 0; i < 16; ++i) {
    const int r = i*4 + (tid >> 6), c = tid & 63;
    t[r][c] = f2bf(w[(size_t)(k0 + r) * N + n0 + c]);
  }
  __syncthreads();
  #pragma unroll
  for (int i = 0; i < 16; ++i) {
    const int r = i*4 + (tid >> 6), c = tid & 63;
    const int n = n0 + r;
    int dr = n;
    if (mode == 1) dr = ((n >> 4) << 5) + (n & 15);
    if (mode == 2) dr = ((n >> 4) << 5) + 16 + (n & 15);
    wt[(size_t)dr * K + k0 + c] = t[c][r];
  }
}

// ---------------------------------------------------------------------------
// V transpose: qkv [ROWS][3072] (v at col 2048) -> vt [32 bh][64 d][2048 t]
// ---------------------------------------------------------------------------
__global__ void vtrans_k(const unsigned short* __restrict__ qkv, unsigned short* __restrict__ vt)
{
  __shared__ unsigned short t[64][65];
  const int tt0 = blockIdx.x * 64;
  const int bh = blockIdx.y, b = bh >> 4, h = bh & 15;
  const int tid = threadIdx.x;
  const unsigned short* src = qkv + (size_t)(b*TSEQ + tt0) * QKVN + 2*DIM + h*HD;
  #pragma unroll
  for (int i = 0; i < 16; ++i) {
    const int r = i*4 + (tid >> 6), c = tid & 63;
    t[r][c] = src[(size_t)r * QKVN + c];
  }
  __syncthreads();
  unsigned short* dst = vt + (size_t)bh * HD * TSEQ + tt0;
  #pragma unroll
  for (int i = 0; i < 16; ++i) {
    const int d = i*4 + (tid >> 6), c = tid & 63;
    dst[(size_t)d * TSEQ + c] = t[c][d];
  }
}

// ---------------------------------------------------------------------------
// RMSNorm: x [ROWS][DIM] fp32 -> out bf16. grid ROWS, block 256.
// ---------------------------------------------------------------------------
__global__ void rmsnorm_k(const float* __restrict__ x, const float* __restrict__ w,
                          unsigned short* __restrict__ o)
{
  const int row = blockIdx.x, tid = threadIdx.x;
  const float4 v = ((const float4*)(x + (size_t)row * DIM))[tid];
  float ss = v.x*v.x + v.y*v.y + v.z*v.z + v.w*v.w;
  #pragma unroll
  for (int off = 32; off >= 1; off >>= 1) ss += __shfl_xor(ss, off);
  __shared__ float sred[4];
  if ((tid & 63) == 0) sred[tid >> 6] = ss;
  __syncthreads();
  const float tot = sred[0] + sred[1] + sred[2] + sred[3];
  const float r = rsqrtf(tot * (1.0f/DIM) + 1e-6f);
  const float4 wv = ((const float4*)w)[tid];
  ushort4 ov;
  ov.x = f2bf(v.x*r*wv.x); ov.y = f2bf(v.y*r*wv.y);
  ov.z = f2bf(v.z*r*wv.z); ov.w = f2bf(v.w*r*wv.w);
  ((ushort4*)(o + (size_t)row * DIM))[tid] = ov;
}

// ---------------------------------------------------------------------------
// GEMM 128x128 (m97 structure) for small-N GEMMs (WO, down).
// ---------------------------------------------------------------------------
template<int EPI>
__global__ void gemm128(const unsigned short* __restrict__ A, int lda,
                        const unsigned short* __restrict__ BT, int ldb,
                        void* __restrict__ Cout, int ldc,
                        const float* __restrict__ res, int K)
{
  __shared__ __align__(16) unsigned short lA[128*64];
  __shared__ __align__(16) unsigned short lB[128*64];
  const int tid = threadIdx.x;
  const int lane = tid & 63;
  const int wid = tid >> 6;
  const int m0 = blockIdx.y * 128, n0 = blockIdx.x * 128;
  const int wr = (wid >> 1) * 64, wc = (wid & 1) * 64;
  const int lrow = lane & 15, lk8 = (lane >> 4) * 8;

  f32x4 acc[4][4] = {};

  for (int k0 = 0; k0 < K; k0 += 64) {
    #pragma unroll
    for (int c = 0; c < 4; ++c) {
      const int boff = c*4096 + tid*16;
      const int row = boff >> 7, colb = boff & 127;
      gld16((const char*)A + ((size_t)(m0+row)*lda + k0)*2 + colb, (char*)lA + boff);
    }
    #pragma unroll
    for (int c = 0; c < 4; ++c) {
      const int boff = c*4096 + tid*16;
      const int row = boff >> 7, colb = boff & 127;
      gld16((const char*)BT + ((size_t)(n0+row)*ldb + k0)*2 + colb, (char*)lB + boff);
    }
    __syncthreads();
    #pragma unroll
    for (int kk = 0; kk < 64; kk += 32) {
      s16x8 af[4], bf[4];
      #pragma unroll
      for (int i = 0; i < 4; ++i) af[i] = *(const s16x8*)&lA[(wr + i*16 + lrow)*64 + kk + lk8];
      #pragma unroll
      for (int j = 0; j < 4; ++j) bf[j] = *(const s16x8*)&lB[(wc + j*16 + lrow)*64 + kk + lk8];
      #pragma unroll
      for (int i = 0; i < 4; ++i)
        #pragma unroll
        for (int j = 0; j < 4; ++j)
          acc[i][j] = __builtin_amdgcn_mfma_f32_16x16x32_bf16(af[i], bf[j], acc[i][j], 0, 0, 0);
    }
    __syncthreads();
  }
  const int er = (lane >> 4) * 4, ec = lane & 15;
  #pragma unroll
  for (int i = 0; i < 4; ++i)
    #pragma unroll
    for (int j = 0; j < 4; ++j) {
      const int gr = m0 + wr + i*16 + er;
      const int gc = n0 + wc + j*16 + ec;
      #pragma unroll
      for (int e = 0; e < 4; ++e) {
        const size_t idx = (size_t)(gr + e) * ldc + gc;
        if (EPI == 0) ((unsigned short*)Cout)[idx] = f2bf(acc[i][j][e]);
        else          ((float*)Cout)[idx] = res[idx] + acc[i][j][e];
      }
    }
}

// ---------------------------------------------------------------------------
// GEMM 256x256, 4-phase interleave, LDS XOR-swizzle, setprio (T2+T3+T5).
// C[M][N] = A[M][K] @ BT[N][K]^T, bf16 in. 512 threads = 8 waves (2M x 4N).
// Per wave: 128x64 output = 8x4 f32x4 frags. BK=64, LDS 128KB double-buffered.
// Stage plan (RACE-SAFE): stage tile t+1 ONLY (into buf cur^1, disjoint from
// all tile-t reads); all 8 gld16 issued at ph0; single vmcnt(0) at ph3
// trailing barrier (loads had ~3 MFMA phases to land).
// Phases: ph0 {rd a0,b0 | STG all | bar | lgkm0 | Q00 | bar}
//         ph1 {rd b1    |         | bar | lgkm0 | Q01 | bar}
//         ph2 {rd a1    |         | bar | lgkm0 | Q11 | bar}
//         ph3 {                   |       Q10 | vmcnt(0) | bar}
// EPI 0: bf16 store (ldc = N). EPI 2: silu(gate)*up pair store to h (ldc=FFN),
//        weights interleaved 16gate/16up per 32-row group.
// ---------------------------------------------------------------------------
template<int EPI>
__global__ __launch_bounds__(512) void gemm256(const unsigned short* __restrict__ A, int lda,
                                               const unsigned short* __restrict__ BT, int ldb,
                                               void* __restrict__ Cout, int ldc, int K)
{
  __shared__ __align__(16) unsigned short lA[2][256*64];
  __shared__ __align__(16) unsigned short lB[2][256*64];
  const int tid = threadIdx.x, lane = tid & 63, wid = tid >> 6;
  const int lrow = lane & 15, g = lane >> 4;
  const int wm = wid >> 2, wn = wid & 3;
  const int m0 = blockIdx.y * 256, n0 = blockIdx.x * 256;

  // staging: thread covers row r0 (and r0+64 per chunk), 16B at phys col (tid&7)*16
  const int r0 = tid >> 3;
  const int lc0 = ((tid & 7) * 16) ^ ((r0 & 7) << 4);   // unswizzled source col
  const char* pA = (const char*)A + ((size_t)(m0 + r0) * lda) * 2 + lc0;
  const char* pB = (const char*)BT + ((size_t)(n0 + r0) * ldb) * 2 + lc0;
  char* dA = (char*)&lA[0][0] + tid * 16;
  char* dB = (char*)&lB[0][0] + tid * 16;
  const size_t a64 = (size_t)64 * lda * 2;
  const size_t b64 = (size_t)64 * ldb * 2;

#define STG_A(t, ah) do { \
    const char* s_ = pA + (size_t)(ah) * 2 * a64 + (size_t)(t) * 128; \
    char* d_ = dA + ((t) & 1) * 32768 + (ah) * 16384; \
    gld16(s_, d_); gld16(s_ + a64, d_ + 8192); } while (0)
#define STG_B(t, bh) do { \
    const char* s_ = pB + (size_t)(bh) * 2 * b64 + (size_t)(t) * 128; \
    char* d_ = dB + ((t) & 1) * 32768 + (bh) * 16384; \
    gld16(s_, d_); gld16(s_ + b64, d_ + 8192); } while (0)

  // frag read addressing (swizzled)
  const int swz = (lrow & 7) << 4;
  const int c0 = (g * 16) ^ swz;
  const int c1 = c0 ^ 64;
  const char* rdA = (const char*)&lA[0][0] + (wm * 128 + lrow) * 128;
  const char* rdB = (const char*)&lB[0][0] + (wn * 64 + lrow) * 128;

  f32x4 acc[8][4] = {};
  s16x8 a0[4][2], a1[4][2], b0[2][2], b1[2][2];

#define MFMA_Q(rh, ch, AF, BF) do { \
    _Pragma("unroll") \
    for (int i_ = 0; i_ < 4; ++i_) { \
      _Pragma("unroll") \
      for (int j_ = 0; j_ < 2; ++j_) { \
        acc[(rh)*4+i_][(ch)*2+j_] = __builtin_amdgcn_mfma_f32_16x16x32_bf16(AF[i_][0], BF[j_][0], acc[(rh)*4+i_][(ch)*2+j_], 0,0,0); \
        acc[(rh)*4+i_][(ch)*2+j_] = __builtin_amdgcn_mfma_f32_16x16x32_bf16(AF[i_][1], BF[j_][1], acc[(rh)*4+i_][(ch)*2+j_], 0,0,0); \
      } } } while (0)

  const int NT = K >> 6;

  // prologue: stage tile 0 only; drain; barrier
  STG_A(0, 0); STG_A(0, 1); STG_B(0, 0); STG_B(0, 1);
  asm volatile("s_waitcnt vmcnt(0)" ::: "memory");
  __builtin_amdgcn_s_barrier();

  for (int t = 0; t < NT; ++t) {
    const char* bufA = rdA + (t & 1) * 32768;
    const char* bufB = rdB + (t & 1) * 32768;
    // ---- ph0: ds a0,b0 | stage ALL of tile t+1 into buf cur^1
    #pragma unroll
    for (int i = 0; i < 4; ++i) {
      a0[i][0] = *(const s16x8*)(bufA + i*2048 + c0);
      a0[i][1] = *(const s16x8*)(bufA + i*2048 + c1);
    }
    #pragma unroll
    for (int j = 0; j < 2; ++j) {
      b0[j][0] = *(const s16x8*)(bufB + j*2048 + c0);
      b0[j][1] = *(const s16x8*)(bufB + j*2048 + c1);
    }
    if (t + 1 < NT) {
      STG_A(t + 1, 0); STG_A(t + 1, 1);
      STG_B(t + 1, 0); STG_B(t + 1, 1);
    }
    __builtin_amdgcn_s_barrier();
    asm volatile("s_waitcnt lgkmcnt(0)" ::: "memory");
    __builtin_amdgcn_sched_barrier(0);
    __builtin_amdgcn_s_setprio(1);
    MFMA_Q(0, 0, a0, b0);
    __builtin_amdgcn_s_setprio(0);
    __builtin_amdgcn_s_barrier();
    // ---- ph1: ds b1
    #pragma unroll
    for (int j = 0; j < 2; ++j) {
      b1[j][0] = *(const s16x8*)(bufB + 4096 + j*2048 + c0);
      b1[j][1] = *(const s16x8*)(bufB + 4096 + j*2048 + c1);
    }
    __builtin_amdgcn_s_barrier();
    asm volatile("s_waitcnt lgkmcnt(0)" ::: "memory");
    __builtin_amdgcn_sched_barrier(0);
    __builtin_amdgcn_s_setprio(1);
    MFMA_Q(0, 1, a0, b1);
    __builtin_amdgcn_s_setprio(0);
    __builtin_amdgcn_s_barrier();
    // ---- ph2: ds a1
    #pragma unroll
    for (int i = 0; i < 4; ++i) {
      a1[i][0] = *(const s16x8*)(bufA + 8192 + i*2048 + c0);
      a1[i][1] = *(const s16x8*)(bufA + 8192 + i*2048 + c1);
    }
    __builtin_amdgcn_s_barrier();
    asm volatile("s_waitcnt lgkmcnt(0)" ::: "memory");
    __builtin_amdgcn_sched_barrier(0);
    __builtin_amdgcn_s_setprio(1);
    MFMA_Q(1, 1, a1, b1);
    __builtin_amdgcn_s_setprio(0);
    __builtin_amdgcn_s_barrier();
    // ---- ph3: no reads, no stage
    __builtin_amdgcn_s_setprio(1);
    MFMA_Q(1, 0, a1, b0);
    __builtin_amdgcn_s_setprio(0);
    if (t + 1 < NT) { asm volatile("s_waitcnt vmcnt(0)" ::: "memory"); }
    __builtin_amdgcn_s_barrier();
  }

  const int er = g * 4, ec = lane & 15;
  if (EPI == 0) {
    unsigned short* C = (unsigned short*)Cout;
    #pragma unroll
    for (int i = 0; i < 8; ++i)
      #pragma unroll
      for (int j = 0; j < 4; ++j) {
        const int gr = m0 + wm*128 + i*16 + er;
        const int gc = n0 + wn*64 + j*16 + ec;
        #pragma unroll
        for (int e = 0; e < 4; ++e)
          C[(size_t)(gr + e) * ldc + gc] = f2bf(acc[i][j][e]);
      }
  } else {
    unsigned short* C = (unsigned short*)Cout;
    #pragma unroll
    for (int i = 0; i < 8; ++i)
      #pragma unroll
      for (int tp = 0; tp < 2; ++tp) {
        const int gr = m0 + wm*128 + i*16 + er;
        const int hc = (n0 >> 1) + wn*32 + tp*16 + ec;
        #pragma unroll
        for (int e = 0; e < 4; ++e) {
          const float gv = acc[i][2*tp][e];
          const float uv = acc[i][2*tp + 1][e];
          const float hv = gv / (1.f + __expf(-gv)) * uv;
          C[(size_t)(gr + e) * ldc + hc] = f2bf(hv);
        }
      }
  }
#undef STG_A
#undef STG_B
#undef MFMA_Q
}

// ---------------------------------------------------------------------------
// Flash attention (causal). grid (T/128, B*H), block 512 (8 waves x 16 q).
// ---------------------------------------------------------------------------
__global__ __launch_bounds__(512) void attn_fwd(const unsigned short* __restrict__ qkv,
                                                const unsigned short* __restrict__ vt,
                                                unsigned short* __restrict__ outp)
{
  __shared__ __align__(16) unsigned short lK[2][64*64];
  __shared__ __align__(16) unsigned short lV[2][64*64];
  const int qblk = blockIdx.x;
  const int bh = blockIdx.y, b = bh >> 4, h = bh & 15;
  const int tid = threadIdx.x, wid = tid >> 6, lane = tid & 63;
  const int lq = lane & 15, g = lane >> 4;

  const int qrow = qblk*128 + wid*16;
  const int myq = qrow + lq;

  const size_t qbase = ((size_t)(b*TSEQ + myq)) * QKVN + h*HD;
  const s16x8 qf0 = *(const s16x8*)&qkv[qbase + g*8];
  const s16x8 qf1 = *(const s16x8*)&qkv[qbase + 32 + g*8];

  const int boff = tid * 16;
  const int loff = boff ^ (((boff >> 7) & 7) << 4);
  const int srow = loff >> 7;
  const int scolb = loff & 127;
  const char* ksrc0 = (const char*)qkv +
      (((size_t)(b*TSEQ + srow)) * QKVN + DIM + h*HD) * 2 + scolb;
  const char* vsrc0 = (const char*)vt +
      (((size_t)bh*HD + srow) * TSEQ) * 2 + scolb;

  float mrun = -INFINITY, lrun = 0.f;
  f32x4 of[4] = {};

  const int nkt = 2*qblk + 2;

  gld16(ksrc0, (char*)lK[0] + boff);
  gld16(vsrc0, (char*)lV[0] + boff);
  int cur = 0;

  for (int kt = 0; kt < nkt; ++kt) {
    __syncthreads();
    if (kt + 1 < nkt) {
      gld16(ksrc0 + (size_t)(kt+1)*64*(QKVN*2), (char*)lK[cur^1] + boff);
      gld16(vsrc0 + (size_t)(kt+1)*128,         (char*)lV[cur^1] + boff);
    }
    if (kt*64 <= qrow + 15) {
      const unsigned short* Kb = lK[cur];
      const unsigned short* Vb = lV[cur];
      f32x4 sacc[4] = {};
      #pragma unroll
      for (int s = 0; s < 4; ++s) {
        const int r = s*16 + lq;
        const int sw = (r & 7) << 4;
        const s16x8 kf0 = *(const s16x8*)((const char*)Kb + r*128 + ((g*16) ^ sw));
        const s16x8 kf1 = *(const s16x8*)((const char*)Kb + r*128 + ((64 + g*16) ^ sw));
        sacc[s] = __builtin_amdgcn_mfma_f32_16x16x32_bf16(kf0, qf0, sacc[s], 0,0,0);
        sacc[s] = __builtin_amdgcn_mfma_f32_16x16x32_bf16(kf1, qf1, sacc[s], 0,0,0);
      }
      float p[4][4];
      float mt = -INFINITY;
      #pragma unroll
      for (int s = 0; s < 4; ++s)
        #pragma unroll
        for (int e = 0; e < 4; ++e) {
          const int key = kt*64 + s*16 + 4*g + e;
          const float v = (key <= myq) ? sacc[s][e]*0.125f : -INFINITY;
          p[s][e] = v;
          mt = fmaxf(mt, v);
        }
      mt = fmaxf(mt, __shfl_xor(mt, 16));
      mt = fmaxf(mt, __shfl_xor(mt, 32));
      const float mnew = fmaxf(mrun, mt);
      const float scale = __expf(mrun - mnew);
      float ssum = 0.f;
      #pragma unroll
      for (int s = 0; s < 4; ++s)
        #pragma unroll
        for (int e = 0; e < 4; ++e) {
          p[s][e] = __expf(p[s][e] - mnew);
          ssum += p[s][e];
        }
      ssum += __shfl_xor(ssum, 16);
      ssum += __shfl_xor(ssum, 32);
      lrun = lrun * scale + ssum;
      mrun = mnew;
      #pragma unroll
      for (int d0b = 0; d0b < 4; ++d0b) of[d0b] = of[d0b] * scale;
      #pragma unroll
      for (int hh = 0; hh < 2; ++hh) {
        unsigned w[4];
        #pragma unroll
        for (int j = 0; j < 4; ++j) w[j] = pack_bf2(p[2*hh][j], p[2*hh+1][j]);
        s16x8 bp;
        #pragma unroll
        for (int e = 0; e < 8; ++e) {
          const int srcg = 2*(g & 1) + (e >> 2);
          const unsigned ww = (unsigned)__shfl((int)w[e & 3], lq | (srcg << 4));
          bp[e] = (short)((g >= 2) ? (ww >> 16) : (ww & 0xffffu));
        }
        #pragma unroll
        for (int d0b = 0; d0b < 4; ++d0b) {
          const int r = d0b*16 + lq;
          const int sw = (r & 7) << 4;
          const s16x8 vf = *(const s16x8*)((const char*)Vb + r*128 + ((hh*64 + g*16) ^ sw));
          of[d0b] = __builtin_amdgcn_mfma_f32_16x16x32_bf16(vf, bp, of[d0b], 0,0,0);
        }
      }
    }
    cur ^= 1;
  }
  const float inv = 1.f / lrun;
  const size_t obase = ((size_t)(b*TSEQ + myq)) * DIM + h*HD;
  #pragma unroll
  for (int d0b = 0; d0b < 4; ++d0b) {
    ushort4 o;
    o.x = f2bf(of[d0b][0] * inv);
    o.y = f2bf(of[d0b][1] * inv);
    o.z = f2bf(of[d0b][2] * inv);
    o.w = f2bf(of[d0b][3] * inv);
    *(ushort4*)&outp[obase + d0b*16 + 4*g] = o;
  }
}

// ---------------------------------------------------------------------------
extern "C" void kernel_launch(void* const* d_in, const int* in_sizes, int n_in,
                              void* d_out, int out_size, void* d_ws, size_t ws_size,
                              hipStream_t stream)
{
  const float* x   = (const float*)d_in[0];
  const float* wq  = (const float*)d_in[1];
  const float* wk  = (const float*)d_in[2];
  const float* wv  = (const float*)d_in[3];
  const float* wo  = (const float*)d_in[4];
  const float* wg  = (const float*)d_in[5];
  const float* wu  = (const float*)d_in[6];
  const float* wd  = (const float*)d_in[7];
  const float* anw = (const float*)d_in[8];
  const float* fnw = (const float*)d_in[9];
  float* outp = (float*)d_out;

  const size_t MB = 1024*1024;
  char* ws = (char*)d_ws;
  unsigned short* wqkvT = (unsigned short*)(ws + 0);        // [3072][1024] 6MB
  unsigned short* woT   = (unsigned short*)(ws + 6*MB);     // [1024][1024] 2MB
  unsigned short* wguT  = (unsigned short*)(ws + 8*MB);     // [8192][1024] 16MB (interleaved)
  unsigned short* wdT   = (unsigned short*)(ws + 24*MB);    // [1024][4096] 8MB
  unsigned short* xn    = (unsigned short*)(ws + 32*MB);    // [4096][1024] 8MB
  float*          x1    = (float*)         (ws + 40*MB);    // [4096][1024] fp32 16MB
  unsigned short* qkv   = (unsigned short*)(ws + 56*MB);    // [4096][3072] 24MB
  unsigned short* vtb   = (unsigned short*)(ws + 80*MB);    // [32][64][2048] 8MB
  unsigned short* aout  = (unsigned short*)(ws + 88*MB);    // [4096][1024] 8MB
  unsigned short* hbuf  = (unsigned short*)(ws + 56*MB);    // [4096][4096] 32MB (aliases qkv..)

  const dim3 blk(256);

  wtrans_k<<<dim3(16,16), blk, 0, stream>>>(wq, wqkvT,               DIM, DIM, 0);
  wtrans_k<<<dim3(16,16), blk, 0, stream>>>(wk, wqkvT + 1024*1024,   DIM, DIM, 0);
  wtrans_k<<<dim3(16,16), blk, 0, stream>>>(wv, wqkvT + 2*1024*1024, DIM, DIM, 0);
  wtrans_k<<<dim3(16,16), blk, 0, stream>>>(wo, woT,                 DIM, DIM, 0);
  wtrans_k<<<dim3(64,16), blk, 0, stream>>>(wg, wguT,                DIM, FFN, 1);
  wtrans_k<<<dim3(64,16), blk, 0, stream>>>(wu, wguT,                DIM, FFN, 2);
  wtrans_k<<<dim3(16,64), blk, 0, stream>>>(wd, wdT,                 FFN, DIM, 0);

  rmsnorm_k<<<ROWS, blk, 0, stream>>>(x, anw, xn);
  gemm256<0><<<dim3(QKVN/256, ROWS/256), dim3(512), 0, stream>>>(xn, DIM, wqkvT, DIM, qkv, QKVN, DIM);
  vtrans_k<<<dim3(TSEQ/64, BATCH*NH), blk, 0, stream>>>(qkv, vtb);
  attn_fwd<<<dim3(TSEQ/128, BATCH*NH), dim3(512), 0, stream>>>(qkv, vtb, aout);
  gemm128<1><<<dim3(DIM/128, ROWS/128), blk, 0, stream>>>(aout, DIM, woT, DIM, x1, DIM, x, DIM);

  rmsnorm_k<<<ROWS, blk, 0, stream>>>(x1, fnw, xn);
  gemm256<2><<<dim3(2*FFN/256, ROWS/256), dim3(512), 0, stream>>>(xn, DIM, wguT, DIM, hbuf, FFN, DIM);
  gemm128<1><<<dim3(DIM/128, ROWS/128), blk, 0, stream>>>(hbuf, FFN, wdT, FFN, (void*)outp, DIM, x1, FFN);
}

// Round 5
// 353.631 us; speedup vs baseline: 1.1599x; 1.0231x over previous
//
#include <hip/hip_runtime.h>
#include <hip/hip_bf16.h>
#include <stdint.h>
#include <math.h>

#define DIM   1024
#define TSEQ  2048
#define BATCH 2
#define NH    16
#define HD    64
#define FFN   4096
#define ROWS  (BATCH*TSEQ)   /* 4096 */
#define QKVN  (3*DIM)        /* 3072 */

typedef __attribute__((ext_vector_type(8))) short s16x8;
typedef __attribute__((ext_vector_type(4))) float f32x4;

__device__ __forceinline__ unsigned short f2bf(float f) {
  union { float f; unsigned u; } v; v.f = f;
  unsigned r = v.u + 0x7fffu + ((v.u >> 16) & 1u);
  return (unsigned short)(r >> 16);
}
__device__ __forceinline__ float bf2f(unsigned short h) {
  union { unsigned u; float f; } v; v.u = ((unsigned)h) << 16; return v.f;
}
__device__ __forceinline__ unsigned pack_bf2(float lo, float hi) {
  union { float f; unsigned u; } a, c; a.f = lo; c.f = hi;
  return (c.u & 0xffff0000u) | (a.u >> 16);
}

__device__ __forceinline__ void gld16(const void* g, void* l) {
  __builtin_amdgcn_global_load_lds((const __attribute__((address_space(1))) void*)g,
                                   (__attribute__((address_space(3))) void*)l, 16, 0, 0);
}

// ---------------------------------------------------------------------------
// Weight transpose+cast: w [K][N] fp32 -> wt [dest(n)][K] bf16. grid (N/64,K/64)
// mode 0: dest=n. mode 1 (gate): dest=(n>>4)*32+(n&15). mode 2 (up): +16.
// ---------------------------------------------------------------------------
__global__ void wtrans_k(const float* __restrict__ w, unsigned short* __restrict__ wt,
                         int K, int N, int mode)
{
  __shared__ unsigned short t[64][65];
  const int n0 = blockIdx.x * 64, k0 = blockIdx.y * 64;
  const int tid = threadIdx.x;
  #pragma unroll
  for (int i = 0; i < 16; ++i) {
    const int r = i*4 + (tid >> 6), c = tid & 63;
    t[r][c] = f2bf(w[(size_t)(k0 + r) * N + n0 + c]);
  }
  __syncthreads();
  #pragma unroll
  for (int i = 0; i < 16; ++i) {
    const int r = i*4 + (tid >> 6), c = tid & 63;
    const int n = n0 + r;
    int dr = n;
    if (mode == 1) dr = ((n >> 4) << 5) + (n & 15);
    if (mode == 2) dr = ((n >> 4) << 5) + 16 + (n & 15);
    wt[(size_t)dr * K + k0 + c] = t[c][r];
  }
}

// ---------------------------------------------------------------------------
// V transpose: qkv [ROWS][3072] (v at col 2048) -> vt [32 bh][64 d][2048 t]
// ---------------------------------------------------------------------------
__global__ void vtrans_k(const unsigned short* __restrict__ qkv, unsigned short* __restrict__ vt)
{
  __shared__ unsigned short t[64][65];
  const int tt0 = blockIdx.x * 64;
  const int bh = blockIdx.y, b = bh >> 4, h = bh & 15;
  const int tid = threadIdx.x;
  const unsigned short* src = qkv + (size_t)(b*TSEQ + tt0) * QKVN + 2*DIM + h*HD;
  #pragma unroll
  for (int i = 0; i < 16; ++i) {
    const int r = i*4 + (tid >> 6), c = tid & 63;
    t[r][c] = src[(size_t)r * QKVN + c];
  }
  __syncthreads();
  unsigned short* dst = vt + (size_t)bh * HD * TSEQ + tt0;
  #pragma unroll
  for (int i = 0; i < 16; ++i) {
    const int d = i*4 + (tid >> 6), c = tid & 63;
    dst[(size_t)d * TSEQ + c] = t[c][d];
  }
}

// ---------------------------------------------------------------------------
// RMSNorm: x [ROWS][DIM] fp32 -> out bf16. grid ROWS, block 256.
// ---------------------------------------------------------------------------
__global__ void rmsnorm_k(const float* __restrict__ x, const float* __restrict__ w,
                          unsigned short* __restrict__ o)
{
  const int row = blockIdx.x, tid = threadIdx.x;
  const float4 v = ((const float4*)(x + (size_t)row * DIM))[tid];
  float ss = v.x*v.x + v.y*v.y + v.z*v.z + v.w*v.w;
  #pragma unroll
  for (int off = 32; off >= 1; off >>= 1) ss += __shfl_xor(ss, off);
  __shared__ float sred[4];
  if ((tid & 63) == 0) sred[tid >> 6] = ss;
  __syncthreads();
  const float tot = sred[0] + sred[1] + sred[2] + sred[3];
  const float r = rsqrtf(tot * (1.0f/DIM) + 1e-6f);
  const float4 wv = ((const float4*)w)[tid];
  ushort4 ov;
  ov.x = f2bf(v.x*r*wv.x); ov.y = f2bf(v.y*r*wv.y);
  ov.z = f2bf(v.z*r*wv.z); ov.w = f2bf(v.w*r*wv.w);
  ((ushort4*)(o + (size_t)row * DIM))[tid] = ov;
}

// ---------------------------------------------------------------------------
// GEMM 128x128 (m97 structure) for small-N GEMMs (WO, down).
// ---------------------------------------------------------------------------
template<int EPI>
__global__ void gemm128(const unsigned short* __restrict__ A, int lda,
                        const unsigned short* __restrict__ BT, int ldb,
                        void* __restrict__ Cout, int ldc,
                        const float* __restrict__ res, int K)
{
  __shared__ __align__(16) unsigned short lA[128*64];
  __shared__ __align__(16) unsigned short lB[128*64];
  const int tid = threadIdx.x;
  const int lane = tid & 63;
  const int wid = tid >> 6;
  const int m0 = blockIdx.y * 128, n0 = blockIdx.x * 128;
  const int wr = (wid >> 1) * 64, wc = (wid & 1) * 64;
  const int lrow = lane & 15, lk8 = (lane >> 4) * 8;

  f32x4 acc[4][4] = {};

  for (int k0 = 0; k0 < K; k0 += 64) {
    #pragma unroll
    for (int c = 0; c < 4; ++c) {
      const int boff = c*4096 + tid*16;
      const int row = boff >> 7, colb = boff & 127;
      gld16((const char*)A + ((size_t)(m0+row)*lda + k0)*2 + colb, (char*)lA + boff);
    }
    #pragma unroll
    for (int c = 0; c < 4; ++c) {
      const int boff = c*4096 + tid*16;
      const int row = boff >> 7, colb = boff & 127;
      gld16((const char*)BT + ((size_t)(n0+row)*ldb + k0)*2 + colb, (char*)lB + boff);
    }
    __syncthreads();
    #pragma unroll
    for (int kk = 0; kk < 64; kk += 32) {
      s16x8 af[4], bf[4];
      #pragma unroll
      for (int i = 0; i < 4; ++i) af[i] = *(const s16x8*)&lA[(wr + i*16 + lrow)*64 + kk + lk8];
      #pragma unroll
      for (int j = 0; j < 4; ++j) bf[j] = *(const s16x8*)&lB[(wc + j*16 + lrow)*64 + kk + lk8];
      #pragma unroll
      for (int i = 0; i < 4; ++i)
        #pragma unroll
        for (int j = 0; j < 4; ++j)
          acc[i][j] = __builtin_amdgcn_mfma_f32_16x16x32_bf16(af[i], bf[j], acc[i][j], 0, 0, 0);
    }
    __syncthreads();
  }
  const int er = (lane >> 4) * 4, ec = lane & 15;
  #pragma unroll
  for (int i = 0; i < 4; ++i)
    #pragma unroll
    for (int j = 0; j < 4; ++j) {
      const int gr = m0 + wr + i*16 + er;
      const int gc = n0 + wc + j*16 + ec;
      #pragma unroll
      for (int e = 0; e < 4; ++e) {
        const size_t idx = (size_t)(gr + e) * ldc + gc;
        if (EPI == 0) ((unsigned short*)Cout)[idx] = f2bf(acc[i][j][e]);
        else          ((float*)Cout)[idx] = res[idx] + acc[i][j][e];
      }
    }
}

// ---------------------------------------------------------------------------
// GEMM 256x256, 4-phase, COUNTED vmcnt (T2+T3+T4+T5). 512 thr = 8 waves (2Mx4N).
// Stage groups match reader phases exactly (wave (wm,wn) reads A rows
// wm*128+[0,64) & B rows wn*64+[0,32) in ph0, etc.):
//   GA0 = A rows [0,64)u[128,192)   read as a0 (ph0)
//   GA1 = A rows [64,128)u[192,256) read as a1 (ph2)
//   GB0 = B rows with bit5==0       read as b0 (ph0)
//   GB1 = B rows with bit5==1       read as b1 (ph1)
// Stage t+1 into buf (t+1)&1 (disjoint from tile-t reads): ph0 issues GA0+GB0,
// ph1 GB1, ph2 GA1. Waits (2 loads/group/wave): end-ph0 vmcnt(6) [GB1(t)],
// end-ph1 vmcnt(6) [GA1(t)], end-ph3 vmcnt(4) [GA0,GB0(t+1)]. Last tile:
// vmcnt(2)/vmcnt(0). Never drains to 0 mid-loop.
// EPI 0: bf16 store. EPI 2: silu(gate)*up fused store (interleaved weights).
// ---------------------------------------------------------------------------
template<int EPI>
__global__ __launch_bounds__(512) void gemm256(const unsigned short* __restrict__ A, int lda,
                                               const unsigned short* __restrict__ BT, int ldb,
                                               void* __restrict__ Cout, int ldc, int K)
{
  __shared__ __align__(16) unsigned short lA[2][256*64];
  __shared__ __align__(16) unsigned short lB[2][256*64];
  const int tid = threadIdx.x, lane = tid & 63, wid = tid >> 6;
  const int lrow = lane & 15, g = lane >> 4;
  const int wm = wid >> 2, wn = wid & 3;
  const int m0 = blockIdx.y * 256, n0 = blockIdx.x * 256;

  // staging geometry
  const int r0 = tid >> 3;                              // [0,64)
  const int eB = ((r0 >> 5) << 6) | (r0 & 31);          // B group base row (bit5=0)
  const int lc0 = ((tid & 7) * 16) ^ ((r0 & 7) << 4);   // pre-swizzled source col
  const char* pA = (const char*)A + ((size_t)(m0 + r0) * lda) * 2 + lc0;
  const char* pB = (const char*)BT + ((size_t)(n0 + eB) * ldb) * 2 + lc0;
  char* dA = (char*)&lA[0][0] + tid * 16;                       // row r0 slot
  char* dB = (char*)&lB[0][0] + eB * 128 + (tid & 7) * 16;      // row eB slot
  const size_t a64 = (size_t)64 * lda * 2;
  const size_t b32 = (size_t)32 * ldb * 2;

#define STG_GA0(t) do { const char* s_ = pA + (size_t)(t) * 128; \
    char* d_ = dA + (((t) & 1) * 32768); \
    gld16(s_, d_); gld16(s_ + 2*a64, d_ + 16384); } while (0)
#define STG_GA1(t) do { const char* s_ = pA + (size_t)(t) * 128 + a64; \
    char* d_ = dA + (((t) & 1) * 32768) + 8192; \
    gld16(s_, d_); gld16(s_ + 2*a64, d_ + 16384); } while (0)
#define STG_GB0(t) do { const char* s_ = pB + (size_t)(t) * 128; \
    char* d_ = dB + (((t) & 1) * 32768); \
    gld16(s_, d_); gld16(s_ + 4*b32, d_ + 16384); } while (0)
#define STG_GB1(t) do { const char* s_ = pB + (size_t)(t) * 128 + b32; \
    char* d_ = dB + (((t) & 1) * 32768) + 4096; \
    gld16(s_, d_); gld16(s_ + 4*b32, d_ + 16384); } while (0)

  // frag read addressing (swizzled)
  const int swz = (lrow & 7) << 4;
  const int c0 = (g * 16) ^ swz;
  const int c1 = c0 ^ 64;
  const char* rdA = (const char*)&lA[0][0] + (wm * 128 + lrow) * 128;
  const char* rdB = (const char*)&lB[0][0] + (wn * 64 + lrow) * 128;

  f32x4 acc[8][4] = {};
  s16x8 a0[4][2], a1[4][2], b0[2][2], b1[2][2];

#define MFMA_Q(rh, ch, AF, BF) do { \
    _Pragma("unroll") \
    for (int i_ = 0; i_ < 4; ++i_) { \
      _Pragma("unroll") \
      for (int j_ = 0; j_ < 2; ++j_) { \
        acc[(rh)*4+i_][(ch)*2+j_] = __builtin_amdgcn_mfma_f32_16x16x32_bf16(AF[i_][0], BF[j_][0], acc[(rh)*4+i_][(ch)*2+j_], 0,0,0); \
        acc[(rh)*4+i_][(ch)*2+j_] = __builtin_amdgcn_mfma_f32_16x16x32_bf16(AF[i_][1], BF[j_][1], acc[(rh)*4+i_][(ch)*2+j_], 0,0,0); \
      } } } while (0)

  const int NT = K >> 6;

  // prologue: stage tile 0 (GA0,GB0 first -> waited first)
  STG_GA0(0); STG_GB0(0); STG_GB1(0); STG_GA1(0);
  asm volatile("s_waitcnt vmcnt(4)" ::: "memory");
  __builtin_amdgcn_s_barrier();

  for (int t = 0; t < NT; ++t) {
    const char* bufA = rdA + (t & 1) * 32768;
    const char* bufB = rdB + (t & 1) * 32768;
    const bool more = (t + 1 < NT);
    // ---- ph0: ds a0,b0 | stage GA0,GB0(t+1)
    #pragma unroll
    for (int i = 0; i < 4; ++i) {
      a0[i][0] = *(const s16x8*)(bufA + i*2048 + c0);
      a0[i][1] = *(const s16x8*)(bufA + i*2048 + c1);
    }
    #pragma unroll
    for (int j = 0; j < 2; ++j) {
      b0[j][0] = *(const s16x8*)(bufB + j*2048 + c0);
      b0[j][1] = *(const s16x8*)(bufB + j*2048 + c1);
    }
    if (more) { STG_GA0(t + 1); STG_GB0(t + 1); }
    __builtin_amdgcn_s_barrier();
    asm volatile("s_waitcnt lgkmcnt(0)" ::: "memory");
    __builtin_amdgcn_sched_barrier(0);
    __builtin_amdgcn_s_setprio(1);
    MFMA_Q(0, 0, a0, b0);
    __builtin_amdgcn_s_setprio(0);
    if (more) { asm volatile("s_waitcnt vmcnt(6)" ::: "memory"); }
    else      { asm volatile("s_waitcnt vmcnt(2)" ::: "memory"); }
    __builtin_amdgcn_s_barrier();
    // ---- ph1: ds b1 | stage GB1(t+1)
    #pragma unroll
    for (int j = 0; j < 2; ++j) {
      b1[j][0] = *(const s16x8*)(bufB + 4096 + j*2048 + c0);
      b1[j][1] = *(const s16x8*)(bufB + 4096 + j*2048 + c1);
    }
    if (more) STG_GB1(t + 1);
    __builtin_amdgcn_s_barrier();
    asm volatile("s_waitcnt lgkmcnt(0)" ::: "memory");
    __builtin_amdgcn_sched_barrier(0);
    __builtin_amdgcn_s_setprio(1);
    MFMA_Q(0, 1, a0, b1);
    __builtin_amdgcn_s_setprio(0);
    if (more) { asm volatile("s_waitcnt vmcnt(6)" ::: "memory"); }
    else      { asm volatile("s_waitcnt vmcnt(0)" ::: "memory"); }
    __builtin_amdgcn_s_barrier();
    // ---- ph2: ds a1 | stage GA1(t+1)
    #pragma unroll
    for (int i = 0; i < 4; ++i) {
      a1[i][0] = *(const s16x8*)(bufA + 8192 + i*2048 + c0);
      a1[i][1] = *(const s16x8*)(bufA + 8192 + i*2048 + c1);
    }
    if (more) STG_GA1(t + 1);
    __builtin_amdgcn_s_barrier();
    asm volatile("s_waitcnt lgkmcnt(0)" ::: "memory");
    __builtin_amdgcn_sched_barrier(0);
    __builtin_amdgcn_s_setprio(1);
    MFMA_Q(1, 1, a1, b1);
    __builtin_amdgcn_s_setprio(0);
    __builtin_amdgcn_s_barrier();
    // ---- ph3: no reads, no stage
    __builtin_amdgcn_s_setprio(1);
    MFMA_Q(1, 0, a1, b0);
    __builtin_amdgcn_s_setprio(0);
    if (more) { asm volatile("s_waitcnt vmcnt(4)" ::: "memory"); }
    __builtin_amdgcn_s_barrier();
  }

  const int er = g * 4, ec = lane & 15;
  if (EPI == 0) {
    unsigned short* C = (unsigned short*)Cout;
    #pragma unroll
    for (int i = 0; i < 8; ++i)
      #pragma unroll
      for (int j = 0; j < 4; ++j) {
        const int gr = m0 + wm*128 + i*16 + er;
        const int gc = n0 + wn*64 + j*16 + ec;
        #pragma unroll
        for (int e = 0; e < 4; ++e)
          C[(size_t)(gr + e) * ldc + gc] = f2bf(acc[i][j][e]);
      }
  } else {
    unsigned short* C = (unsigned short*)Cout;
    #pragma unroll
    for (int i = 0; i < 8; ++i)
      #pragma unroll
      for (int tp = 0; tp < 2; ++tp) {
        const int gr = m0 + wm*128 + i*16 + er;
        const int hc = (n0 >> 1) + wn*32 + tp*16 + ec;
        #pragma unroll
        for (int e = 0; e < 4; ++e) {
          const float gv = acc[i][2*tp][e];
          const float uv = acc[i][2*tp + 1][e];
          const float hv = gv / (1.f + __expf(-gv)) * uv;
          C[(size_t)(gr + e) * ldc + hc] = f2bf(hv);
        }
      }
  }
#undef STG_GA0
#undef STG_GA1
#undef STG_GB0
#undef STG_GB1
#undef MFMA_Q
}

// ---------------------------------------------------------------------------
// Flash attention (causal). grid (T/128, B*H), block 512 (8 waves x 16 q).
// ---------------------------------------------------------------------------
__global__ __launch_bounds__(512) void attn_fwd(const unsigned short* __restrict__ qkv,
                                                const unsigned short* __restrict__ vt,
                                                unsigned short* __restrict__ outp)
{
  __shared__ __align__(16) unsigned short lK[2][64*64];
  __shared__ __align__(16) unsigned short lV[2][64*64];
  const int qblk = blockIdx.x;
  const int bh = blockIdx.y, b = bh >> 4, h = bh & 15;
  const int tid = threadIdx.x, wid = tid >> 6, lane = tid & 63;
  const int lq = lane & 15, g = lane >> 4;

  const int qrow = qblk*128 + wid*16;
  const int myq = qrow + lq;

  const size_t qbase = ((size_t)(b*TSEQ + myq)) * QKVN + h*HD;
  const s16x8 qf0 = *(const s16x8*)&qkv[qbase + g*8];
  const s16x8 qf1 = *(const s16x8*)&qkv[qbase + 32 + g*8];

  const int boff = tid * 16;
  const int loff = boff ^ (((boff >> 7) & 7) << 4);
  const int srow = loff >> 7;
  const int scolb = loff & 127;
  const char* ksrc0 = (const char*)qkv +
      (((size_t)(b*TSEQ + srow)) * QKVN + DIM + h*HD) * 2 + scolb;
  const char* vsrc0 = (const char*)vt +
      (((size_t)bh*HD + srow) * TSEQ) * 2 + scolb;

  float mrun = -INFINITY, lrun = 0.f;
  f32x4 of[4] = {};

  const int nkt = 2*qblk + 2;

  gld16(ksrc0, (char*)lK[0] + boff);
  gld16(vsrc0, (char*)lV[0] + boff);
  int cur = 0;

  for (int kt = 0; kt < nkt; ++kt) {
    __syncthreads();
    if (kt + 1 < nkt) {
      gld16(ksrc0 + (size_t)(kt+1)*64*(QKVN*2), (char*)lK[cur^1] + boff);
      gld16(vsrc0 + (size_t)(kt+1)*128,         (char*)lV[cur^1] + boff);
    }
    if (kt*64 <= qrow + 15) {
      const unsigned short* Kb = lK[cur];
      const unsigned short* Vb = lV[cur];
      f32x4 sacc[4] = {};
      #pragma unroll
      for (int s = 0; s < 4; ++s) {
        const int r = s*16 + lq;
        const int sw = (r & 7) << 4;
        const s16x8 kf0 = *(const s16x8*)((const char*)Kb + r*128 + ((g*16) ^ sw));
        const s16x8 kf1 = *(const s16x8*)((const char*)Kb + r*128 + ((64 + g*16) ^ sw));
        sacc[s] = __builtin_amdgcn_mfma_f32_16x16x32_bf16(kf0, qf0, sacc[s], 0,0,0);
        sacc[s] = __builtin_amdgcn_mfma_f32_16x16x32_bf16(kf1, qf1, sacc[s], 0,0,0);
      }
      float p[4][4];
      float mt = -INFINITY;
      #pragma unroll
      for (int s = 0; s < 4; ++s)
        #pragma unroll
        for (int e = 0; e < 4; ++e) {
          const int key = kt*64 + s*16 + 4*g + e;
          const float v = (key <= myq) ? sacc[s][e]*0.125f : -INFINITY;
          p[s][e] = v;
          mt = fmaxf(mt, v);
        }
      mt = fmaxf(mt, __shfl_xor(mt, 16));
      mt = fmaxf(mt, __shfl_xor(mt, 32));
      const float mnew = fmaxf(mrun, mt);
      const float scale = __expf(mrun - mnew);
      float ssum = 0.f;
      #pragma unroll
      for (int s = 0; s < 4; ++s)
        #pragma unroll
        for (int e = 0; e < 4; ++e) {
          p[s][e] = __expf(p[s][e] - mnew);
          ssum += p[s][e];
        }
      ssum += __shfl_xor(ssum, 16);
      ssum += __shfl_xor(ssum, 32);
      lrun = lrun * scale + ssum;
      mrun = mnew;
      #pragma unroll
      for (int d0b = 0; d0b < 4; ++d0b) of[d0b] = of[d0b] * scale;
      #pragma unroll
      for (int hh = 0; hh < 2; ++hh) {
        unsigned w[4];
        #pragma unroll
        for (int j = 0; j < 4; ++j) w[j] = pack_bf2(p[2*hh][j], p[2*hh+1][j]);
        s16x8 bp;
        #pragma unroll
        for (int e = 0; e < 8; ++e) {
          const int srcg = 2*(g & 1) + (e >> 2);
          const unsigned ww = (unsigned)__shfl((int)w[e & 3], lq | (srcg << 4));
          bp[e] = (short)((g >= 2) ? (ww >> 16) : (ww & 0xffffu));
        }
        #pragma unroll
        for (int d0b = 0; d0b < 4; ++d0b) {
          const int r = d0b*16 + lq;
          const int sw = (r & 7) << 4;
          const s16x8 vf = *(const s16x8*)((const char*)Vb + r*128 + ((hh*64 + g*16) ^ sw));
          of[d0b] = __builtin_amdgcn_mfma_f32_16x16x32_bf16(vf, bp, of[d0b], 0,0,0);
        }
      }
    }
    cur ^= 1;
  }
  const float inv = 1.f / lrun;
  const size_t obase = ((size_t)(b*TSEQ + myq)) * DIM + h*HD;
  #pragma unroll
  for (int d0b = 0; d0b < 4; ++d0b) {
    ushort4 o;
    o.x = f2bf(of[d0b][0] * inv);
    o.y = f2bf(of[d0b][1] * inv);
    o.z = f2bf(of[d0b][2] * inv);
    o.w = f2bf(of[d0b][3] * inv);
    *(ushort4*)&outp[obase + d0b*16 + 4*g] = o;
  }
}

// ---------------------------------------------------------------------------
extern "C" void kernel_launch(void* const* d_in, const int* in_sizes, int n_in,
                              void* d_out, int out_size, void* d_ws, size_t ws_size,
                              hipStream_t stream)
{
  const float* x   = (const float*)d_in[0];
  const float* wq  = (const float*)d_in[1];
  const float* wk  = (const float*)d_in[2];
  const float* wv  = (const float*)d_in[3];
  const float* wo  = (const float*)d_in[4];
  const float* wg  = (const float*)d_in[5];
  const float* wu  = (const float*)d_in[6];
  const float* wd  = (const float*)d_in[7];
  const float* anw = (const float*)d_in[8];
  const float* fnw = (const float*)d_in[9];
  float* outp = (float*)d_out;

  const size_t MB = 1024*1024;
  char* ws = (char*)d_ws;
  unsigned short* wqkvT = (unsigned short*)(ws + 0);        // [3072][1024] 6MB
  unsigned short* woT   = (unsigned short*)(ws + 6*MB);     // [1024][1024] 2MB
  unsigned short* wguT  = (unsigned short*)(ws + 8*MB);     // [8192][1024] 16MB (interleaved)
  unsigned short* wdT   = (unsigned short*)(ws + 24*MB);    // [1024][4096] 8MB
  unsigned short* xn    = (unsigned short*)(ws + 32*MB);    // [4096][1024] 8MB
  float*          x1    = (float*)         (ws + 40*MB);    // [4096][1024] fp32 16MB
  unsigned short* qkv   = (unsigned short*)(ws + 56*MB);    // [4096][3072] 24MB
  unsigned short* vtb   = (unsigned short*)(ws + 80*MB);    // [32][64][2048] 8MB
  unsigned short* aout  = (unsigned short*)(ws + 88*MB);    // [4096][1024] 8MB
  unsigned short* hbuf  = (unsigned short*)(ws + 56*MB);    // [4096][4096] 32MB (aliases qkv..)

  const dim3 blk(256);

  wtrans_k<<<dim3(16,16), blk, 0, stream>>>(wq, wqkvT,               DIM, DIM, 0);
  wtrans_k<<<dim3(16,16), blk, 0, stream>>>(wk, wqkvT + 1024*1024,   DIM, DIM, 0);
  wtrans_k<<<dim3(16,16), blk, 0, stream>>>(wv, wqkvT + 2*1024*1024, DIM, DIM, 0);
  wtrans_k<<<dim3(16,16), blk, 0, stream>>>(wo, woT,                 DIM, DIM, 0);
  wtrans_k<<<dim3(64,16), blk, 0, stream>>>(wg, wguT,                DIM, FFN, 1);
  wtrans_k<<<dim3(64,16), blk, 0, stream>>>(wu, wguT,                DIM, FFN, 2);
  wtrans_k<<<dim3(16,64), blk, 0, stream>>>(wd, wdT,                 FFN, DIM, 0);

  rmsnorm_k<<<ROWS, blk, 0, stream>>>(x, anw, xn);
  gemm256<0><<<dim3(QKVN/256, ROWS/256), dim3(512), 0, stream>>>(xn, DIM, wqkvT, DIM, qkv, QKVN, DIM);
  vtrans_k<<<dim3(TSEQ/64, BATCH*NH), blk, 0, stream>>>(qkv, vtb);
  attn_fwd<<<dim3(TSEQ/128, BATCH*NH), dim3(512), 0, stream>>>(qkv, vtb, aout);
  gemm128<1><<<dim3(DIM/128, ROWS/128), blk, 0, stream>>>(aout, DIM, woT, DIM, x1, DIM, x, DIM);

  rmsnorm_k<<<ROWS, blk, 0, stream>>>(x1, fnw, xn);
  gemm256<2><<<dim3(2*FFN/256, ROWS/256), dim3(512), 0, stream>>>(xn, DIM, wguT, DIM, hbuf, FFN, DIM);
  gemm128<1><<<dim3(DIM/128, ROWS/128), blk, 0, stream>>>(hbuf, FFN, wdT, FFN, (void*)outp, DIM, x1, FFN);
}

// Round 6
// 321.654 us; speedup vs baseline: 1.2752x; 1.0994x over previous
//
#include <hip/hip_runtime.h>
#include <hip/hip_bf16.h>
#include <stdint.h>
#include <math.h>

#define DIM   1024
#define TSEQ  2048
#define BATCH 2
#define NH    16
#define HD    64
#define FFN   4096
#define ROWS  (BATCH*TSEQ)   /* 4096 */
#define QKVN  (3*DIM)        /* 3072 */

typedef __attribute__((ext_vector_type(8))) short s16x8;
typedef __attribute__((ext_vector_type(4))) float f32x4;

__device__ __forceinline__ unsigned short f2bf(float f) {
  union { float f; unsigned u; } v; v.f = f;
  unsigned r = v.u + 0x7fffu + ((v.u >> 16) & 1u);
  return (unsigned short)(r >> 16);
}
__device__ __forceinline__ float bf2f(unsigned short h) {
  union { unsigned u; float f; } v; v.u = ((unsigned)h) << 16; return v.f;
}
__device__ __forceinline__ unsigned pack_bf2(float lo, float hi) {
  union { float f; unsigned u; } a, c; a.f = lo; c.f = hi;
  return (c.u & 0xffff0000u) | (a.u >> 16);
}

__device__ __forceinline__ void gld16(const void* g, void* l) {
  __builtin_amdgcn_global_load_lds((const __attribute__((address_space(1))) void*)g,
                                   (__attribute__((address_space(3))) void*)l, 16, 0, 0);
}

// XCD-aware chunked swizzle (m157): valid when nwg % 8 == 0 (all our grids).
// hw block b runs on XCD b%8; logical id (b%8)*(nwg/8)+b/8 gives each XCD a
// contiguous logical chunk -> neighbor tiles share the XCD-private L2.
__device__ __forceinline__ int xcd_swz_flat() {
  const int nx = gridDim.x, ny = gridDim.y;
  const int nwg = nx * ny * gridDim.z;
  const int flat = blockIdx.x + nx * (blockIdx.y + ny * blockIdx.z);
  return (flat & 7) * (nwg >> 3) + (flat >> 3);
}

// ---------------------------------------------------------------------------
// Weight transpose+cast: w [K][N] fp32 -> wt [dest(n)][K] bf16. grid (N/64,K/64)
// mode 0: dest=n. mode 1 (gate): dest=(n>>4)*32+(n&15). mode 2 (up): +16.
// ---------------------------------------------------------------------------
__global__ void wtrans_k(const float* __restrict__ w, unsigned short* __restrict__ wt,
                         int K, int N, int mode)
{
  __shared__ unsigned short t[64][65];
  const int n0 = blockIdx.x * 64, k0 = blockIdx.y * 64;
  const int tid = threadIdx.x;
  #pragma unroll
  for (int i = 0; i < 16; ++i) {
    const int r = i*4 + (tid >> 6), c = tid & 63;
    t[r][c] = f2bf(w[(size_t)(k0 + r) * N + n0 + c]);
  }
  __syncthreads();
  #pragma unroll
  for (int i = 0; i < 16; ++i) {
    const int r = i*4 + (tid >> 6), c = tid & 63;
    const int n = n0 + r;
    int dr = n;
    if (mode == 1) dr = ((n >> 4) << 5) + (n & 15);
    if (mode == 2) dr = ((n >> 4) << 5) + 16 + (n & 15);
    wt[(size_t)dr * K + k0 + c] = t[c][r];
  }
}

// ---------------------------------------------------------------------------
// V transpose: qkv [ROWS][3072] (v at col 2048) -> vt [32 bh][64 d][2048 t]
// ---------------------------------------------------------------------------
__global__ void vtrans_k(const unsigned short* __restrict__ qkv, unsigned short* __restrict__ vt)
{
  __shared__ unsigned short t[64][65];
  const int tt0 = blockIdx.x * 64;
  const int bh = blockIdx.y, b = bh >> 4, h = bh & 15;
  const int tid = threadIdx.x;
  const unsigned short* src = qkv + (size_t)(b*TSEQ + tt0) * QKVN + 2*DIM + h*HD;
  #pragma unroll
  for (int i = 0; i < 16; ++i) {
    const int r = i*4 + (tid >> 6), c = tid & 63;
    t[r][c] = src[(size_t)r * QKVN + c];
  }
  __syncthreads();
  unsigned short* dst = vt + (size_t)bh * HD * TSEQ + tt0;
  #pragma unroll
  for (int i = 0; i < 16; ++i) {
    const int d = i*4 + (tid >> 6), c = tid & 63;
    dst[(size_t)d * TSEQ + c] = t[c][d];
  }
}

// ---------------------------------------------------------------------------
// RMSNorm: x [ROWS][DIM] fp32 -> out bf16. grid ROWS, block 256.
// ---------------------------------------------------------------------------
__global__ void rmsnorm_k(const float* __restrict__ x, const float* __restrict__ w,
                          unsigned short* __restrict__ o)
{
  const int row = blockIdx.x, tid = threadIdx.x;
  const float4 v = ((const float4*)(x + (size_t)row * DIM))[tid];
  float ss = v.x*v.x + v.y*v.y + v.z*v.z + v.w*v.w;
  #pragma unroll
  for (int off = 32; off >= 1; off >>= 1) ss += __shfl_xor(ss, off);
  __shared__ float sred[4];
  if ((tid & 63) == 0) sred[tid >> 6] = ss;
  __syncthreads();
  const float tot = sred[0] + sred[1] + sred[2] + sred[3];
  const float r = rsqrtf(tot * (1.0f/DIM) + 1e-6f);
  const float4 wv = ((const float4*)w)[tid];
  ushort4 ov;
  ov.x = f2bf(v.x*r*wv.x); ov.y = f2bf(v.y*r*wv.y);
  ov.z = f2bf(v.z*r*wv.z); ov.w = f2bf(v.w*r*wv.w);
  ((ushort4*)(o + (size_t)row * DIM))[tid] = ov;
}

// ---------------------------------------------------------------------------
// RMSNorm3: x1 = x + p0 + p1 (fp32 store); xn = rmsnorm(x1)*w (bf16 store).
// Fuses the WO split-K reduce + residual + FFN norm. grid ROWS, block 256.
// ---------------------------------------------------------------------------
__global__ void rmsnorm3_k(const float* __restrict__ x, const float* __restrict__ p0,
                           const float* __restrict__ p1, const float* __restrict__ w,
                           float* __restrict__ x1, unsigned short* __restrict__ o)
{
  const int row = blockIdx.x, tid = threadIdx.x;
  const size_t base = (size_t)row * DIM;
  const float4 a = ((const float4*)(x + base))[tid];
  const float4 b = ((const float4*)(p0 + base))[tid];
  const float4 c = ((const float4*)(p1 + base))[tid];
  float4 v;
  v.x = a.x + b.x + c.x; v.y = a.y + b.y + c.y;
  v.z = a.z + b.z + c.z; v.w = a.w + b.w + c.w;
  ((float4*)(x1 + base))[tid] = v;
  float ss = v.x*v.x + v.y*v.y + v.z*v.z + v.w*v.w;
  #pragma unroll
  for (int off = 32; off >= 1; off >>= 1) ss += __shfl_xor(ss, off);
  __shared__ float sred[4];
  if ((tid & 63) == 0) sred[tid >> 6] = ss;
  __syncthreads();
  const float tot = sred[0] + sred[1] + sred[2] + sred[3];
  const float r = rsqrtf(tot * (1.0f/DIM) + 1e-6f);
  const float4 wv = ((const float4*)w)[tid];
  ushort4 ov;
  ov.x = f2bf(v.x*r*wv.x); ov.y = f2bf(v.y*r*wv.y);
  ov.z = f2bf(v.z*r*wv.z); ov.w = f2bf(v.w*r*wv.w);
  ((ushort4*)(o + base))[tid] = ov;
}

// ---------------------------------------------------------------------------
// Final reduce: out = x1 + q0 + q1 (all fp32). grid 4096, block 256 (float4).
// ---------------------------------------------------------------------------
__global__ void resadd3_k(const float* __restrict__ x1, const float* __restrict__ q0,
                          const float* __restrict__ q1, float* __restrict__ o)
{
  const size_t i = (size_t)blockIdx.x * 256 + threadIdx.x;
  const float4 a = ((const float4*)x1)[i];
  const float4 b = ((const float4*)q0)[i];
  const float4 c = ((const float4*)q1)[i];
  float4 v;
  v.x = a.x + b.x + c.x; v.y = a.y + b.y + c.y;
  v.z = a.z + b.z + c.z; v.w = a.w + b.w + c.w;
  ((float4*)o)[i] = v;
}

// ---------------------------------------------------------------------------
// GEMM 128x128 split-K (m97 structure + XCD swizzle). grid (N/128, M/128, 2).
// Split z computes K range [z*Khalf, (z+1)*Khalf) and stores fp32 partial to
// P + z*M*ldc. 2 blocks/CU (32KB LDS) -> inter-block latency hiding.
// ---------------------------------------------------------------------------
__global__ void gemm128sp(const unsigned short* __restrict__ A, int lda,
                          const unsigned short* __restrict__ BT, int ldb,
                          float* __restrict__ P, int ldc, int Khalf)
{
  __shared__ __align__(16) unsigned short lA[128*64];
  __shared__ __align__(16) unsigned short lB[128*64];
  const int nx = gridDim.x, ny = gridDim.y;
  const int w = xcd_swz_flat();
  const int bx = w % nx, by = (w / nx) % ny, bz = w / (nx * ny);
  const int tid = threadIdx.x;
  const int lane = tid & 63;
  const int wid = tid >> 6;
  const int m0 = by * 128, n0 = bx * 128;
  const int Koff = bz * Khalf;
  P += (size_t)bz * ((size_t)ny * 128) * ldc;
  const int wr = (wid >> 1) * 64, wc = (wid & 1) * 64;
  const int lrow = lane & 15, lk8 = (lane >> 4) * 8;

  f32x4 acc[4][4] = {};

  for (int k0 = Koff; k0 < Koff + Khalf; k0 += 64) {
    #pragma unroll
    for (int c = 0; c < 4; ++c) {
      const int boff = c*4096 + tid*16;
      const int row = boff >> 7, colb = boff & 127;
      gld16((const char*)A + ((size_t)(m0+row)*lda + k0)*2 + colb, (char*)lA + boff);
    }
    #pragma unroll
    for (int c = 0; c < 4; ++c) {
      const int boff = c*4096 + tid*16;
      const int row = boff >> 7, colb = boff & 127;
      gld16((const char*)BT + ((size_t)(n0+row)*ldb + k0)*2 + colb, (char*)lB + boff);
    }
    __syncthreads();
    #pragma unroll
    for (int kk = 0; kk < 64; kk += 32) {
      s16x8 af[4], bf[4];
      #pragma unroll
      for (int i = 0; i < 4; ++i) af[i] = *(const s16x8*)&lA[(wr + i*16 + lrow)*64 + kk + lk8];
      #pragma unroll
      for (int j = 0; j < 4; ++j) bf[j] = *(const s16x8*)&lB[(wc + j*16 + lrow)*64 + kk + lk8];
      #pragma unroll
      for (int i = 0; i < 4; ++i)
        #pragma unroll
        for (int j = 0; j < 4; ++j)
          acc[i][j] = __builtin_amdgcn_mfma_f32_16x16x32_bf16(af[i], bf[j], acc[i][j], 0, 0, 0);
    }
    __syncthreads();
  }
  const int er = (lane >> 4) * 4, ec = lane & 15;
  #pragma unroll
  for (int i = 0; i < 4; ++i)
    #pragma unroll
    for (int j = 0; j < 4; ++j) {
      const int gr = m0 + wr + i*16 + er;
      const int gc = n0 + wc + j*16 + ec;
      #pragma unroll
      for (int e = 0; e < 4; ++e)
        P[(size_t)(gr + e) * ldc + gc] = acc[i][j][e];
    }
}

// ---------------------------------------------------------------------------
// GEMM 256x256, 4-phase, COUNTED vmcnt (T2+T3+T4+T5) + XCD swizzle.
// 512 thr = 8 waves (2Mx4N). See round-5 comments for the stage-group ledger.
// EPI 0: bf16 store. EPI 2: silu(gate)*up fused store (interleaved weights).
// ---------------------------------------------------------------------------
template<int EPI>
__global__ __launch_bounds__(512) void gemm256(const unsigned short* __restrict__ A, int lda,
                                               const unsigned short* __restrict__ BT, int ldb,
                                               void* __restrict__ Cout, int ldc, int K)
{
  __shared__ __align__(16) unsigned short lA[2][256*64];
  __shared__ __align__(16) unsigned short lB[2][256*64];
  const int nx = gridDim.x;
  const int wsz = xcd_swz_flat();
  const int bx = wsz % nx, by = wsz / nx;
  const int tid = threadIdx.x, lane = tid & 63, wid = tid >> 6;
  const int lrow = lane & 15, g = lane >> 4;
  const int wm = wid >> 2, wn = wid & 3;
  const int m0 = by * 256, n0 = bx * 256;

  // staging geometry
  const int r0 = tid >> 3;                              // [0,64)
  const int eB = ((r0 >> 5) << 6) | (r0 & 31);          // B group base row (bit5=0)
  const int lc0 = ((tid & 7) * 16) ^ ((r0 & 7) << 4);   // pre-swizzled source col
  const char* pA = (const char*)A + ((size_t)(m0 + r0) * lda) * 2 + lc0;
  const char* pB = (const char*)BT + ((size_t)(n0 + eB) * ldb) * 2 + lc0;
  char* dA = (char*)&lA[0][0] + tid * 16;                       // row r0 slot
  char* dB = (char*)&lB[0][0] + eB * 128 + (tid & 7) * 16;      // row eB slot
  const size_t a64 = (size_t)64 * lda * 2;
  const size_t b32 = (size_t)32 * ldb * 2;

#define STG_GA0(t) do { const char* s_ = pA + (size_t)(t) * 128; \
    char* d_ = dA + (((t) & 1) * 32768); \
    gld16(s_, d_); gld16(s_ + 2*a64, d_ + 16384); } while (0)
#define STG_GA1(t) do { const char* s_ = pA + (size_t)(t) * 128 + a64; \
    char* d_ = dA + (((t) & 1) * 32768) + 8192; \
    gld16(s_, d_); gld16(s_ + 2*a64, d_ + 16384); } while (0)
#define STG_GB0(t) do { const char* s_ = pB + (size_t)(t) * 128; \
    char* d_ = dB + (((t) & 1) * 32768); \
    gld16(s_, d_); gld16(s_ + 4*b32, d_ + 16384); } while (0)
#define STG_GB1(t) do { const char* s_ = pB + (size_t)(t) * 128 + b32; \
    char* d_ = dB + (((t) & 1) * 32768) + 4096; \
    gld16(s_, d_); gld16(s_ + 4*b32, d_ + 16384); } while (0)

  // frag read addressing (swizzled)
  const int swz = (lrow & 7) << 4;
  const int c0 = (g * 16) ^ swz;
  const int c1 = c0 ^ 64;
  const char* rdA = (const char*)&lA[0][0] + (wm * 128 + lrow) * 128;
  const char* rdB = (const char*)&lB[0][0] + (wn * 64 + lrow) * 128;

  f32x4 acc[8][4] = {};
  s16x8 a0[4][2], a1[4][2], b0[2][2], b1[2][2];

#define MFMA_Q(rh, ch, AF, BF) do { \
    _Pragma("unroll") \
    for (int i_ = 0; i_ < 4; ++i_) { \
      _Pragma("unroll") \
      for (int j_ = 0; j_ < 2; ++j_) { \
        acc[(rh)*4+i_][(ch)*2+j_] = __builtin_amdgcn_mfma_f32_16x16x32_bf16(AF[i_][0], BF[j_][0], acc[(rh)*4+i_][(ch)*2+j_], 0,0,0); \
        acc[(rh)*4+i_][(ch)*2+j_] = __builtin_amdgcn_mfma_f32_16x16x32_bf16(AF[i_][1], BF[j_][1], acc[(rh)*4+i_][(ch)*2+j_], 0,0,0); \
      } } } while (0)

  const int NT = K >> 6;

  // prologue: stage tile 0 (GA0,GB0 first -> waited first)
  STG_GA0(0); STG_GB0(0); STG_GB1(0); STG_GA1(0);
  asm volatile("s_waitcnt vmcnt(4)" ::: "memory");
  __builtin_amdgcn_s_barrier();

  for (int t = 0; t < NT; ++t) {
    const char* bufA = rdA + (t & 1) * 32768;
    const char* bufB = rdB + (t & 1) * 32768;
    const bool more = (t + 1 < NT);
    // ---- ph0: ds a0,b0 | stage GA0,GB0(t+1)
    #pragma unroll
    for (int i = 0; i < 4; ++i) {
      a0[i][0] = *(const s16x8*)(bufA + i*2048 + c0);
      a0[i][1] = *(const s16x8*)(bufA + i*2048 + c1);
    }
    #pragma unroll
    for (int j = 0; j < 2; ++j) {
      b0[j][0] = *(const s16x8*)(bufB + j*2048 + c0);
      b0[j][1] = *(const s16x8*)(bufB + j*2048 + c1);
    }
    if (more) { STG_GA0(t + 1); STG_GB0(t + 1); }
    __builtin_amdgcn_s_barrier();
    asm volatile("s_waitcnt lgkmcnt(0)" ::: "memory");
    __builtin_amdgcn_sched_barrier(0);
    __builtin_amdgcn_s_setprio(1);
    MFMA_Q(0, 0, a0, b0);
    __builtin_amdgcn_s_setprio(0);
    if (more) { asm volatile("s_waitcnt vmcnt(6)" ::: "memory"); }
    else      { asm volatile("s_waitcnt vmcnt(2)" ::: "memory"); }
    __builtin_amdgcn_s_barrier();
    // ---- ph1: ds b1 | stage GB1(t+1)
    #pragma unroll
    for (int j = 0; j < 2; ++j) {
      b1[j][0] = *(const s16x8*)(bufB + 4096 + j*2048 + c0);
      b1[j][1] = *(const s16x8*)(bufB + 4096 + j*2048 + c1);
    }
    if (more) STG_GB1(t + 1);
    __builtin_amdgcn_s_barrier();
    asm volatile("s_waitcnt lgkmcnt(0)" ::: "memory");
    __builtin_amdgcn_sched_barrier(0);
    __builtin_amdgcn_s_setprio(1);
    MFMA_Q(0, 1, a0, b1);
    __builtin_amdgcn_s_setprio(0);
    if (more) { asm volatile("s_waitcnt vmcnt(6)" ::: "memory"); }
    else      { asm volatile("s_waitcnt vmcnt(0)" ::: "memory"); }
    __builtin_amdgcn_s_barrier();
    // ---- ph2: ds a1 | stage GA1(t+1)
    #pragma unroll
    for (int i = 0; i < 4; ++i) {
      a1[i][0] = *(const s16x8*)(bufA + 8192 + i*2048 + c0);
      a1[i][1] = *(const s16x8*)(bufA + 8192 + i*2048 + c1);
    }
    if (more) STG_GA1(t + 1);
    __builtin_amdgcn_s_barrier();
    asm volatile("s_waitcnt lgkmcnt(0)" ::: "memory");
    __builtin_amdgcn_sched_barrier(0);
    __builtin_amdgcn_s_setprio(1);
    MFMA_Q(1, 1, a1, b1);
    __builtin_amdgcn_s_setprio(0);
    __builtin_amdgcn_s_barrier();
    // ---- ph3: no reads, no stage
    __builtin_amdgcn_s_setprio(1);
    MFMA_Q(1, 0, a1, b0);
    __builtin_amdgcn_s_setprio(0);
    if (more) { asm volatile("s_waitcnt vmcnt(4)" ::: "memory"); }
    __builtin_amdgcn_s_barrier();
  }

  const int er = g * 4, ec = lane & 15;
  if (EPI == 0) {
    unsigned short* C = (unsigned short*)Cout;
    #pragma unroll
    for (int i = 0; i < 8; ++i)
      #pragma unroll
      for (int j = 0; j < 4; ++j) {
        const int gr = m0 + wm*128 + i*16 + er;
        const int gc = n0 + wn*64 + j*16 + ec;
        #pragma unroll
        for (int e = 0; e < 4; ++e)
          C[(size_t)(gr + e) * ldc + gc] = f2bf(acc[i][j][e]);
      }
  } else {
    unsigned short* C = (unsigned short*)Cout;
    #pragma unroll
    for (int i = 0; i < 8; ++i)
      #pragma unroll
      for (int tp = 0; tp < 2; ++tp) {
        const int gr = m0 + wm*128 + i*16 + er;
        const int hc = (n0 >> 1) + wn*32 + tp*16 + ec;
        #pragma unroll
        for (int e = 0; e < 4; ++e) {
          const float gv = acc[i][2*tp][e];
          const float uv = acc[i][2*tp + 1][e];
          const float hv = gv / (1.f + __expf(-gv)) * uv;
          C[(size_t)(gr + e) * ldc + hc] = f2bf(hv);
        }
      }
  }
#undef STG_GA0
#undef STG_GA1
#undef STG_GB0
#undef STG_GB1
#undef MFMA_Q
}

// ---------------------------------------------------------------------------
// Flash attention (causal). grid (T/128, B*H), block 512 (8 waves x 16 q).
// ---------------------------------------------------------------------------
__global__ __launch_bounds__(512) void attn_fwd(const unsigned short* __restrict__ qkv,
                                                const unsigned short* __restrict__ vt,
                                                unsigned short* __restrict__ outp)
{
  __shared__ __align__(16) unsigned short lK[2][64*64];
  __shared__ __align__(16) unsigned short lV[2][64*64];
  const int nx = gridDim.x;
  const int wsz = xcd_swz_flat();
  const int qblk = wsz % nx;
  const int bh = wsz / nx, b = bh >> 4, h = bh & 15;
  const int tid = threadIdx.x, wid = tid >> 6, lane = tid & 63;
  const int lq = lane & 15, g = lane >> 4;

  const int qrow = qblk*128 + wid*16;
  const int myq = qrow + lq;

  const size_t qbase = ((size_t)(b*TSEQ + myq)) * QKVN + h*HD;
  const s16x8 qf0 = *(const s16x8*)&qkv[qbase + g*8];
  const s16x8 qf1 = *(const s16x8*)&qkv[qbase + 32 + g*8];

  const int boff = tid * 16;
  const int loff = boff ^ (((boff >> 7) & 7) << 4);
  const int srow = loff >> 7;
  const int scolb = loff & 127;
  const char* ksrc0 = (const char*)qkv +
      (((size_t)(b*TSEQ + srow)) * QKVN + DIM + h*HD) * 2 + scolb;
  const char* vsrc0 = (const char*)vt +
      (((size_t)bh*HD + srow) * TSEQ) * 2 + scolb;

  float mrun = -INFINITY, lrun = 0.f;
  f32x4 of[4] = {};

  const int nkt = 2*qblk + 2;

  gld16(ksrc0, (char*)lK[0] + boff);
  gld16(vsrc0, (char*)lV[0] + boff);
  int cur = 0;

  for (int kt = 0; kt < nkt; ++kt) {
    __syncthreads();
    if (kt + 1 < nkt) {
      gld16(ksrc0 + (size_t)(kt+1)*64*(QKVN*2), (char*)lK[cur^1] + boff);
      gld16(vsrc0 + (size_t)(kt+1)*128,         (char*)lV[cur^1] + boff);
    }
    if (kt*64 <= qrow + 15) {
      const unsigned short* Kb = lK[cur];
      const unsigned short* Vb = lV[cur];
      f32x4 sacc[4] = {};
      #pragma unroll
      for (int s = 0; s < 4; ++s) {
        const int r = s*16 + lq;
        const int sw = (r & 7) << 4;
        const s16x8 kf0 = *(const s16x8*)((const char*)Kb + r*128 + ((g*16) ^ sw));
        const s16x8 kf1 = *(const s16x8*)((const char*)Kb + r*128 + ((64 + g*16) ^ sw));
        sacc[s] = __builtin_amdgcn_mfma_f32_16x16x32_bf16(kf0, qf0, sacc[s], 0,0,0);
        sacc[s] = __builtin_amdgcn_mfma_f32_16x16x32_bf16(kf1, qf1, sacc[s], 0,0,0);
      }
      float p[4][4];
      float mt = -INFINITY;
      #pragma unroll
      for (int s = 0; s < 4; ++s)
        #pragma unroll
        for (int e = 0; e < 4; ++e) {
          const int key = kt*64 + s*16 + 4*g + e;
          const float v = (key <= myq) ? sacc[s][e]*0.125f : -INFINITY;
          p[s][e] = v;
          mt = fmaxf(mt, v);
        }
      mt = fmaxf(mt, __shfl_xor(mt, 16));
      mt = fmaxf(mt, __shfl_xor(mt, 32));
      const float mnew = fmaxf(mrun, mt);
      const float scale = __expf(mrun - mnew);
      float ssum = 0.f;
      #pragma unroll
      for (int s = 0; s < 4; ++s)
        #pragma unroll
        for (int e = 0; e < 4; ++e) {
          p[s][e] = __expf(p[s][e] - mnew);
          ssum += p[s][e];
        }
      ssum += __shfl_xor(ssum, 16);
      ssum += __shfl_xor(ssum, 32);
      lrun = lrun * scale + ssum;
      mrun = mnew;
      #pragma unroll
      for (int d0b = 0; d0b < 4; ++d0b) of[d0b] = of[d0b] * scale;
      #pragma unroll
      for (int hh = 0; hh < 2; ++hh) {
        unsigned w[4];
        #pragma unroll
        for (int j = 0; j < 4; ++j) w[j] = pack_bf2(p[2*hh][j], p[2*hh+1][j]);
        s16x8 bp;
        #pragma unroll
        for (int e = 0; e < 8; ++e) {
          const int srcg = 2*(g & 1) + (e >> 2);
          const unsigned ww = (unsigned)__shfl((int)w[e & 3], lq | (srcg << 4));
          bp[e] = (short)((g >= 2) ? (ww >> 16) : (ww & 0xffffu));
        }
        #pragma unroll
        for (int d0b = 0; d0b < 4; ++d0b) {
          const int r = d0b*16 + lq;
          const int sw = (r & 7) << 4;
          const s16x8 vf = *(const s16x8*)((const char*)Vb + r*128 + ((hh*64 + g*16) ^ sw));
          of[d0b] = __builtin_amdgcn_mfma_f32_16x16x32_bf16(vf, bp, of[d0b], 0,0,0);
        }
      }
    }
    cur ^= 1;
  }
  const float inv = 1.f / lrun;
  const size_t obase = ((size_t)(b*TSEQ + myq)) * DIM + h*HD;
  #pragma unroll
  for (int d0b = 0; d0b < 4; ++d0b) {
    ushort4 o;
    o.x = f2bf(of[d0b][0] * inv);
    o.y = f2bf(of[d0b][1] * inv);
    o.z = f2bf(of[d0b][2] * inv);
    o.w = f2bf(of[d0b][3] * inv);
    *(ushort4*)&outp[obase + d0b*16 + 4*g] = o;
  }
}

// ---------------------------------------------------------------------------
// Workspace layout (96 MB peak, phase-aliased):
//   0..16   x1 (fp32 residual after attn)      [alive rmsnorm3 -> end]
//  16..24   wdT                                 [alive all]
//  24..40   wguT                 | down q0      (wguT dead after gate/up)
//  40..46   wqkvT                | down q1 ...  (dead after QKV)
//  46..48   woT                  | ... q1 cont  (dead after WO)
//  48..56   xn                   | ... q1 cont  (dead after gate/up)
//  56..88   qkv(24)+vtb(8) -> WO p0/p1 -> hbuf(32)
//  88..96   aout                                [dead after WO]
// ---------------------------------------------------------------------------
extern "C" void kernel_launch(void* const* d_in, const int* in_sizes, int n_in,
                              void* d_out, int out_size, void* d_ws, size_t ws_size,
                              hipStream_t stream)
{
  const float* x   = (const float*)d_in[0];
  const float* wq  = (const float*)d_in[1];
  const float* wk  = (const float*)d_in[2];
  const float* wv  = (const float*)d_in[3];
  const float* wo  = (const float*)d_in[4];
  const float* wg  = (const float*)d_in[5];
  const float* wu  = (const float*)d_in[6];
  const float* wd  = (const float*)d_in[7];
  const float* anw = (const float*)d_in[8];
  const float* fnw = (const float*)d_in[9];
  float* outp = (float*)d_out;

  const size_t MB = 1024*1024;
  char* ws = (char*)d_ws;
  float*          x1    = (float*)         (ws + 0);
  unsigned short* wdT   = (unsigned short*)(ws + 16*MB);
  unsigned short* wguT  = (unsigned short*)(ws + 24*MB);
  unsigned short* wqkvT = (unsigned short*)(ws + 40*MB);
  unsigned short* woT   = (unsigned short*)(ws + 46*MB);
  unsigned short* xn    = (unsigned short*)(ws + 48*MB);
  unsigned short* qkv   = (unsigned short*)(ws + 56*MB);
  unsigned short* vtb   = (unsigned short*)(ws + 80*MB);
  unsigned short* aout  = (unsigned short*)(ws + 88*MB);
  float*          pwo   = (float*)         (ws + 56*MB);   // 2 x 16MB WO partials
  unsigned short* hbuf  = (unsigned short*)(ws + 56*MB);   // 32MB
  float*          pdn   = (float*)         (ws + 24*MB);   // 2 x 16MB down partials

  const dim3 blk(256);

  wtrans_k<<<dim3(16,16), blk, 0, stream>>>(wq, wqkvT,               DIM, DIM, 0);
  wtrans_k<<<dim3(16,16), blk, 0, stream>>>(wk, wqkvT + 1024*1024,   DIM, DIM, 0);
  wtrans_k<<<dim3(16,16), blk, 0, stream>>>(wv, wqkvT + 2*1024*1024, DIM, DIM, 0);
  wtrans_k<<<dim3(16,16), blk, 0, stream>>>(wo, woT,                 DIM, DIM, 0);
  wtrans_k<<<dim3(64,16), blk, 0, stream>>>(wg, wguT,                DIM, FFN, 1);
  wtrans_k<<<dim3(64,16), blk, 0, stream>>>(wu, wguT,                DIM, FFN, 2);
  wtrans_k<<<dim3(16,64), blk, 0, stream>>>(wd, wdT,                 FFN, DIM, 0);

  // attention path
  rmsnorm_k<<<ROWS, blk, 0, stream>>>(x, anw, xn);
  gemm256<0><<<dim3(QKVN/256, ROWS/256), dim3(512), 0, stream>>>(xn, DIM, wqkvT, DIM, qkv, QKVN, DIM);
  vtrans_k<<<dim3(TSEQ/64, BATCH*NH), blk, 0, stream>>>(qkv, vtb);
  attn_fwd<<<dim3(TSEQ/128, BATCH*NH), dim3(512), 0, stream>>>(qkv, vtb, aout);
  // WO: split-K=2 -> fp32 partials, reduced+residual+norm in rmsnorm3
  gemm128sp<<<dim3(DIM/128, ROWS/128, 2), blk, 0, stream>>>(aout, DIM, woT, DIM, pwo, DIM, DIM/2);
  rmsnorm3_k<<<ROWS, blk, 0, stream>>>(x, pwo, pwo + (size_t)ROWS*DIM, fnw, x1, xn);

  // ffn path
  gemm256<2><<<dim3(2*FFN/256, ROWS/256), dim3(512), 0, stream>>>(xn, DIM, wguT, DIM, hbuf, FFN, DIM);
  gemm128sp<<<dim3(DIM/128, ROWS/128, 2), blk, 0, stream>>>(hbuf, FFN, wdT, FFN, pdn, DIM, FFN/2);
  resadd3_k<<<dim3(ROWS*DIM/1024), blk, 0, stream>>>(x1, pdn, pdn + (size_t)ROWS*DIM, outp);
}